// Round 1
// baseline (1131.500 us; speedup 1.0000x reference)
//
#include <hip/hip_runtime.h>
#include <cstdint>

#define NEG_SLOPE 0.2f

// ---------- preprocessing ----------

__global__ void k_deg_sum(const int* __restrict__ dst, const float* __restrict__ ea,
                          float* __restrict__ sum_attr, int* __restrict__ deg, int E) {
    int e = blockIdx.x * blockDim.x + threadIdx.x;
    if (e >= E) return;
    int d = dst[e];
    atomicAdd(deg + d, 1);
    const float* a = ea + (size_t)e * 8;
    float* s = sum_attr + (size_t)d * 8;
#pragma unroll
    for (int k = 0; k < 8; k++) atomicAdd(s + k, a[k]);
}

__global__ void k_finish_mean(float* __restrict__ mean_attr, const int* __restrict__ deg, int n) {
    int idx = blockIdx.x * blockDim.x + threadIdx.x;
    if (idx >= n * 8) return;
    int i = idx >> 3;
    int d = deg[i]; if (d < 1) d = 1;
    mean_attr[idx] *= (1.0f / (float)d);
}

__global__ void k_scan_block(const int* __restrict__ in, int* __restrict__ out,
                             int* __restrict__ partials, int n) {
    __shared__ int s[256];
    int i = blockIdx.x * 256 + threadIdx.x;
    int v = (i < n) ? in[i] : 0;
    s[threadIdx.x] = v;
    __syncthreads();
    for (int off = 1; off < 256; off <<= 1) {
        int t = (threadIdx.x >= off) ? s[threadIdx.x - off] : 0;
        __syncthreads();
        s[threadIdx.x] += t;
        __syncthreads();
    }
    if (i < n) out[i] = s[threadIdx.x] - v;   // exclusive
    if (threadIdx.x == 255) partials[blockIdx.x] = s[255];
}

__global__ void k_scan_partials(int* __restrict__ partials, int nb) {
    __shared__ int s[256];
    int v = (threadIdx.x < nb) ? partials[threadIdx.x] : 0;
    s[threadIdx.x] = v;
    __syncthreads();
    for (int off = 1; off < 256; off <<= 1) {
        int t = (threadIdx.x >= off) ? s[threadIdx.x - off] : 0;
        __syncthreads();
        s[threadIdx.x] += t;
        __syncthreads();
    }
    if (threadIdx.x < nb) partials[threadIdx.x] = s[threadIdx.x] - v;  // exclusive
}

__global__ void k_add_offsets(int* __restrict__ rowstart, int* __restrict__ cursor,
                              const int* __restrict__ partials, int n) {
    int i = blockIdx.x * 256 + threadIdx.x;
    if (i >= n) return;
    int r = rowstart[i] + partials[blockIdx.x];
    rowstart[i] = r;
    cursor[i] = r;
}

__global__ void k_fill_csr(const int* __restrict__ dst, int* __restrict__ cursor,
                           int* __restrict__ eid, int E) {
    int e = blockIdx.x * blockDim.x + threadIdx.x;
    if (e >= E) return;
    int pos = atomicAdd(cursor + dst[e], 1);
    eid[pos] = e;
}

// ---------- per-layer kernels ----------

template<int DIN, int DOUT>
__global__ void k_gemm(const float* __restrict__ X, const float* __restrict__ W,
                       float* __restrict__ H, int n) {
    int idx = blockIdx.x * blockDim.x + threadIdx.x;
    if (idx >= n * DOUT) return;
    int row = idx / DOUT;
    int col = idx - row * DOUT;
    const float* x = X + (size_t)row * DIN;
    float acc = 0.f;
#pragma unroll 8
    for (int k = 0; k < DIN; k++) acc = fmaf(x[k], W[(size_t)k * DOUT + col], acc);
    H[idx] = acc;
}

template<int DOUT>
__global__ void k_node_dots(const float* __restrict__ H, const float* __restrict__ as_,
                            const float* __restrict__ ad_, float* __restrict__ hs,
                            float* __restrict__ hd, int n) {
    int t = blockIdx.x * blockDim.x + threadIdx.x;
    int wid = t >> 6, lane = t & 63;
    if (wid >= n) return;
    const float* h = H + (size_t)wid * DOUT;
    float a = 0.f, b = 0.f;
#pragma unroll
    for (int k = lane; k < DOUT; k += 64) {
        float v = h[k];
        a = fmaf(v, as_[k], a);
        b = fmaf(v, ad_[k], b);
    }
#pragma unroll
    for (int off = 32; off; off >>= 1) {
        a += __shfl_xor(a, off);
        b += __shfl_xor(b, off);
    }
    if (lane == 0) { hs[wid] = a; hd[wid] = b; }
}

template<int DOUT>
__global__ void k_wea(const float* __restrict__ We, const float* __restrict__ ae,
                      float* __restrict__ wea) {
    int j = threadIdx.x;
    if (j < 8) {
        float s = 0.f;
        for (int k = 0; k < DOUT; k++) s = fmaf(We[(size_t)j * DOUT + k], ae[k], s);
        wea[j] = s;
    }
}

__global__ void k_edge_alpha(const int* __restrict__ src, const int* __restrict__ dst,
                             const float* __restrict__ ea, const float* __restrict__ mean_attr,
                             const float* __restrict__ hs, const float* __restrict__ hd,
                             const float* __restrict__ wea, float* __restrict__ alpha,
                             int E, int n) {
    int e = blockIdx.x * blockDim.x + threadIdx.x;
    if (e >= E + n) return;
    int s, d;
    const float* a;
    if (e < E) { s = src[e]; d = dst[e]; a = ea + (size_t)e * 8; }
    else       { s = e - E;  d = s;      a = mean_attr + (size_t)s * 8; }
    float al = hs[s] + hd[d];
#pragma unroll
    for (int k = 0; k < 8; k++) al = fmaf(a[k], wea[k], al);
    alpha[e] = al > 0.f ? al : NEG_SLOPE * al;
}

template<int DOUT, bool RELU>
__global__ void k_aggregate(const float* __restrict__ H, const int* __restrict__ rowstart,
                            const int* __restrict__ deg, const int* __restrict__ eid,
                            const int* __restrict__ src, const float* __restrict__ alpha,
                            const float* __restrict__ alpha_self, const float* __restrict__ bias,
                            float* __restrict__ out, int n) {
    int t = blockIdx.x * blockDim.x + threadIdx.x;
    int wid = t >> 6, lane = t & 63;
    if (wid >= n) return;
    int start = rowstart[wid], d = deg[wid];
    float aself = alpha_self[wid];

    // segment max (lane-parallel then wave reduce)
    float m = aself;
    for (int j = lane; j < d; j += 64) m = fmaxf(m, alpha[eid[start + j]]);
#pragma unroll
    for (int off = 32; off; off >>= 1) m = fmaxf(m, __shfl_xor(m, off));

    constexpr int V = DOUT / 64;
    float acc[V];
    float denom;
    {
        float w = expf(aself - m);
        denom = w;
        const float* h = H + (size_t)wid * DOUT;
#pragma unroll
        for (int v = 0; v < V; v++) acc[v] = w * h[lane * V + v];
    }
    for (int j = 0; j < d; j++) {
        int e = eid[start + j];
        float w = expf(alpha[e] - m);
        denom += w;
        const float* h = H + (size_t)src[e] * DOUT;
#pragma unroll
        for (int v = 0; v < V; v++) acc[v] = fmaf(w, h[lane * V + v], acc[v]);
    }
    float inv = 1.0f / (denom + 1e-16f);
#pragma unroll
    for (int v = 0; v < V; v++) {
        float o = acc[v] * inv + bias[lane * V + v];
        if (RELU) o = fmaxf(o, 0.f);
        out[(size_t)wid * DOUT + lane * V + v] = o;
    }
}

// ---------- launch ----------

extern "C" void kernel_launch(void* const* d_in, const int* in_sizes, int n_in,
                              void* d_out, int out_size, void* d_ws, size_t ws_size,
                              hipStream_t stream) {
    const float* x     = (const float*)d_in[0];
    const int*   eidx  = (const int*)d_in[1];
    const float* eattr = (const float*)d_in[2];
    const int N = in_sizes[0] / 128;
    const int E = in_sizes[1] / 2;
    const int* src = eidx;
    const int* dst = eidx + E;

    char* ws = (char*)d_ws;
    size_t off = 0;
    auto alloc = [&](size_t bytes) -> void* {
        void* p = ws + off;
        off += (bytes + 255) & ~(size_t)255;
        return p;
    };
    float* bufA      = (float*)alloc((size_t)N * 128 * sizeof(float));
    float* hbuf      = (float*)alloc((size_t)N * 128 * sizeof(float));
    float* mean_attr = (float*)alloc((size_t)N * 8 * sizeof(float));
    int*   deg       = (int*)alloc((size_t)N * sizeof(int));
    int*   rowstart  = (int*)alloc((size_t)N * sizeof(int));
    int*   cursor    = (int*)alloc((size_t)N * sizeof(int));
    float* hs        = (float*)alloc((size_t)N * sizeof(float));
    float* hd        = (float*)alloc((size_t)N * sizeof(float));
    float* alpha     = (float*)alloc((size_t)(E + N) * sizeof(float));
    int*   eid       = (int*)alloc((size_t)E * sizeof(int));
    float* wea       = (float*)alloc(64 * sizeof(float));
    int*   partials  = (int*)alloc(256 * sizeof(int));

    const int tb = 256;
    hipMemsetAsync(mean_attr, 0, (size_t)N * 8 * sizeof(float), stream);
    hipMemsetAsync(deg, 0, (size_t)N * sizeof(int), stream);

    k_deg_sum<<<(E + tb - 1) / tb, tb, 0, stream>>>(dst, eattr, mean_attr, deg, E);
    k_finish_mean<<<(N * 8 + tb - 1) / tb, tb, 0, stream>>>(mean_attr, deg, N);
    int nb = (N + 255) / 256;
    k_scan_block<<<nb, 256, 0, stream>>>(deg, rowstart, partials, N);
    k_scan_partials<<<1, 256, 0, stream>>>(partials, nb);
    k_add_offsets<<<nb, 256, 0, stream>>>(rowstart, cursor, partials, N);
    k_fill_csr<<<(E + tb - 1) / tb, tb, 0, stream>>>(dst, cursor, eid, E);

    int nwave_blocks = (N * 64 + tb - 1) / tb;

    // ---- layer 0 (DIN=128, DOUT=128, relu) ----
    {
        const float* W   = (const float*)d_in[3];
        const float* as_ = (const float*)d_in[4];
        const float* ad_ = (const float*)d_in[5];
        const float* We  = (const float*)d_in[6];
        const float* ae  = (const float*)d_in[7];
        const float* b   = (const float*)d_in[8];
        k_gemm<128, 128><<<(N * 128 + tb - 1) / tb, tb, 0, stream>>>(x, W, hbuf, N);
        k_node_dots<128><<<nwave_blocks, tb, 0, stream>>>(hbuf, as_, ad_, hs, hd, N);
        k_wea<128><<<1, 64, 0, stream>>>(We, ae, wea);
        k_edge_alpha<<<(E + N + tb - 1) / tb, tb, 0, stream>>>(src, dst, eattr, mean_attr, hs, hd, wea, alpha, E, N);
        k_aggregate<128, true><<<nwave_blocks, tb, 0, stream>>>(hbuf, rowstart, deg, eid, src, alpha, alpha + E, b, bufA, N);
    }
    // ---- layer 1 (DIN=128, DOUT=128, relu) ----
    {
        const float* W   = (const float*)d_in[9];
        const float* as_ = (const float*)d_in[10];
        const float* ad_ = (const float*)d_in[11];
        const float* We  = (const float*)d_in[12];
        const float* ae  = (const float*)d_in[13];
        const float* b   = (const float*)d_in[14];
        k_gemm<128, 128><<<(N * 128 + tb - 1) / tb, tb, 0, stream>>>(bufA, W, hbuf, N);
        k_node_dots<128><<<nwave_blocks, tb, 0, stream>>>(hbuf, as_, ad_, hs, hd, N);
        k_wea<128><<<1, 64, 0, stream>>>(We, ae, wea);
        k_edge_alpha<<<(E + N + tb - 1) / tb, tb, 0, stream>>>(src, dst, eattr, mean_attr, hs, hd, wea, alpha, E, N);
        k_aggregate<128, true><<<nwave_blocks, tb, 0, stream>>>(hbuf, rowstart, deg, eid, src, alpha, alpha + E, b, bufA, N);
    }
    // ---- layer 2 (DIN=128, DOUT=64, no relu) ----
    {
        const float* W   = (const float*)d_in[15];
        const float* as_ = (const float*)d_in[16];
        const float* ad_ = (const float*)d_in[17];
        const float* We  = (const float*)d_in[18];
        const float* ae  = (const float*)d_in[19];
        const float* b   = (const float*)d_in[20];
        k_gemm<128, 64><<<(N * 64 + tb - 1) / tb, tb, 0, stream>>>(bufA, W, hbuf, N);
        k_node_dots<64><<<nwave_blocks, tb, 0, stream>>>(hbuf, as_, ad_, hs, hd, N);
        k_wea<64><<<1, 64, 0, stream>>>(We, ae, wea);
        k_edge_alpha<<<(E + N + tb - 1) / tb, tb, 0, stream>>>(src, dst, eattr, mean_attr, hs, hd, wea, alpha, E, N);
        k_aggregate<64, false><<<nwave_blocks, tb, 0, stream>>>(hbuf, rowstart, deg, eid, src, alpha, alpha + E, b, (float*)d_out, N);
    }
}

// Round 2
// 551.231 us; speedup vs baseline: 2.0527x; 2.0527x over previous
//
#include <hip/hip_runtime.h>
#include <cstdint>

#define NEG_SLOPE 0.2f

// ---------- preprocessing ----------

__global__ void k_count(const int* __restrict__ dst, int* __restrict__ deg, int E) {
    int e = blockIdx.x * blockDim.x + threadIdx.x;
    if (e < E) atomicAdd(deg + dst[e], 1);
}

__global__ void k_scan_block(const int* __restrict__ in, int* __restrict__ out,
                             int* __restrict__ partials, int n) {
    __shared__ int s[256];
    int i = blockIdx.x * 256 + threadIdx.x;
    int v = (i < n) ? in[i] : 0;
    s[threadIdx.x] = v;
    __syncthreads();
    for (int off = 1; off < 256; off <<= 1) {
        int t = (threadIdx.x >= off) ? s[threadIdx.x - off] : 0;
        __syncthreads();
        s[threadIdx.x] += t;
        __syncthreads();
    }
    if (i < n) out[i] = s[threadIdx.x] - v;   // exclusive
    if (threadIdx.x == 255) partials[blockIdx.x] = s[255];
}

__global__ void k_scan_partials(int* __restrict__ partials, int nb) {
    __shared__ int s[256];
    int v = (threadIdx.x < nb) ? partials[threadIdx.x] : 0;
    s[threadIdx.x] = v;
    __syncthreads();
    for (int off = 1; off < 256; off <<= 1) {
        int t = (threadIdx.x >= off) ? s[threadIdx.x - off] : 0;
        __syncthreads();
        s[threadIdx.x] += t;
        __syncthreads();
    }
    if (threadIdx.x < nb) partials[threadIdx.x] = s[threadIdx.x] - v;  // exclusive
}

__global__ void k_add_offsets(int* __restrict__ rowstart, int* __restrict__ cursor,
                              const int* __restrict__ partials, int n) {
    int i = blockIdx.x * 256 + threadIdx.x;
    if (i >= n) return;
    int r = rowstart[i] + partials[blockIdx.x];
    rowstart[i] = r;
    cursor[i] = r;
}

__global__ void k_fill_csr(const int* __restrict__ dst, int* __restrict__ cursor,
                           int* __restrict__ eid, int E) {
    int e = blockIdx.x * blockDim.x + threadIdx.x;
    if (e >= E) return;
    int pos = atomicAdd(cursor + dst[e], 1);
    eid[pos] = e;
}

// wave per node: lanes (j0*8+k) sum attr k of edges j0, j0+8, ... then reduce
__global__ void k_mean_csr(const float* __restrict__ ea, const int* __restrict__ rowstart,
                           const int* __restrict__ deg, const int* __restrict__ eid,
                           float* __restrict__ mean_attr, int n) {
    int t = blockIdx.x * blockDim.x + threadIdx.x;
    int wid = t >> 6, lane = t & 63;
    if (wid >= n) return;
    int start = rowstart[wid], d = deg[wid];
    int j0 = lane >> 3, k = lane & 7;
    float s = 0.f;
    for (int j = j0; j < d; j += 8) s += ea[(size_t)eid[start + j] * 8 + k];
    s += __shfl_xor(s, 8);
    s += __shfl_xor(s, 16);
    s += __shfl_xor(s, 32);
    if (lane < 8) {
        int dd = d < 1 ? 1 : d;
        mean_attr[(size_t)wid * 8 + lane] = s / (float)dd;
    }
}

// ---------- fused GEMM + attention dots ----------
// Block: 256 threads. W fully staged in LDS, BM-row X tile in LDS.
// Each thread computes a 4x4 register tile; hs/hd reduced from live accumulators.

template<int DIN, int DOUT>
__global__ __launch_bounds__(256) void k_gemm_dots(
    const float* __restrict__ X, const float* __restrict__ W,
    const float* __restrict__ as_, const float* __restrict__ ad_,
    float* __restrict__ H, float* __restrict__ hs, float* __restrict__ hd, int n)
{
    constexpr int GROUP = DOUT / 4;     // threads per row-quad (32 or 16)
    constexpr int BM = 1024 / GROUP;    // rows per block (32 or 64)
    __shared__ float sW[DIN * DOUT];
    __shared__ float sX[BM * DIN];

    int tid = threadIdx.x;
    int row_base = blockIdx.x * BM;

    { // load W as float4
        constexpr int WV = DIN * DOUT / 4;
        const float4* Wv = (const float4*)W;
        float4* sWv = (float4*)sW;
#pragma unroll
        for (int i = tid; i < WV; i += 256) sWv[i] = Wv[i];
    }
    { // load X tile as float4 (guard tail rows)
        int rows_avail = n - row_base; if (rows_avail > BM) rows_avail = BM;
        int xlim = rows_avail * DIN / 4;
        const float4* Xv = (const float4*)(X + (size_t)row_base * DIN);
        float4* sXv = (float4*)sX;
        for (int i = tid; i < xlim; i += 256) sXv[i] = Xv[i];
    }
    __syncthreads();

    int r0 = (tid / GROUP) * 4;
    int c0 = (tid % GROUP) * 4;

    float acc[4][4] = {};
#pragma unroll 4
    for (int k = 0; k < DIN; k++) {
        float4 w = *(const float4*)&sW[k * DOUT + c0];
        float xv[4];
#pragma unroll
        for (int i = 0; i < 4; i++) xv[i] = sX[(r0 + i) * DIN + k];
#pragma unroll
        for (int i = 0; i < 4; i++) {
            acc[i][0] = fmaf(xv[i], w.x, acc[i][0]);
            acc[i][1] = fmaf(xv[i], w.y, acc[i][1]);
            acc[i][2] = fmaf(xv[i], w.z, acc[i][2]);
            acc[i][3] = fmaf(xv[i], w.w, acc[i][3]);
        }
    }

    float4 av = *(const float4*)&as_[c0];
    float4 dv = *(const float4*)&ad_[c0];

#pragma unroll
    for (int i = 0; i < 4; i++) {
        int row = row_base + r0 + i;
        bool ok = row < n;
        if (ok) {
            float4 o = { acc[i][0], acc[i][1], acc[i][2], acc[i][3] };
            *(float4*)&H[(size_t)row * DOUT + c0] = o;
        }
        float ps = acc[i][0] * av.x + acc[i][1] * av.y + acc[i][2] * av.z + acc[i][3] * av.w;
        float pd = acc[i][0] * dv.x + acc[i][1] * dv.y + acc[i][2] * dv.z + acc[i][3] * dv.w;
#pragma unroll
        for (int off = GROUP / 2; off; off >>= 1) {
            ps += __shfl_xor(ps, off);
            pd += __shfl_xor(pd, off);
        }
        if (ok && (tid % GROUP) == 0) { hs[row] = ps; hd[row] = pd; }
    }
}

// ---------- per-layer edge/aggregate kernels ----------

template<int DOUT>
__global__ void k_wea(const float* __restrict__ We, const float* __restrict__ ae,
                      float* __restrict__ wea) {
    int j = threadIdx.x;
    if (j < 8) {
        float s = 0.f;
        for (int k = 0; k < DOUT; k++) s = fmaf(We[(size_t)j * DOUT + k], ae[k], s);
        wea[j] = s;
    }
}

__global__ void k_edge_alpha(const int* __restrict__ src, const int* __restrict__ dst,
                             const float* __restrict__ ea, const float* __restrict__ mean_attr,
                             const float* __restrict__ hs, const float* __restrict__ hd,
                             const float* __restrict__ wea, float* __restrict__ alpha,
                             int E, int n) {
    int e = blockIdx.x * blockDim.x + threadIdx.x;
    if (e >= E + n) return;
    int s, d;
    const float* a;
    if (e < E) { s = src[e]; d = dst[e]; a = ea + (size_t)e * 8; }
    else       { s = e - E;  d = s;      a = mean_attr + (size_t)s * 8; }
    float4 a0 = *(const float4*)a;
    float4 a1 = *(const float4*)(a + 4);
    float4 w0 = *(const float4*)wea;
    float4 w1 = *(const float4*)(wea + 4);
    float al = hs[s] + hd[d];
    al = fmaf(a0.x, w0.x, al); al = fmaf(a0.y, w0.y, al);
    al = fmaf(a0.z, w0.z, al); al = fmaf(a0.w, w0.w, al);
    al = fmaf(a1.x, w1.x, al); al = fmaf(a1.y, w1.y, al);
    al = fmaf(a1.z, w1.z, al); al = fmaf(a1.w, w1.w, al);
    alpha[e] = al > 0.f ? al : NEG_SLOPE * al;
}

template<int DOUT, bool RELU>
__global__ void k_aggregate(const float* __restrict__ H, const int* __restrict__ rowstart,
                            const int* __restrict__ deg, const int* __restrict__ eid,
                            const int* __restrict__ src, const float* __restrict__ alpha,
                            const float* __restrict__ alpha_self, const float* __restrict__ bias,
                            float* __restrict__ out, int n) {
    int t = blockIdx.x * blockDim.x + threadIdx.x;
    int wid = t >> 6, lane = t & 63;
    if (wid >= n) return;
    int start = rowstart[wid], d = deg[wid];
    float aself = alpha_self[wid];

    float m = aself;
    for (int j = lane; j < d; j += 64) m = fmaxf(m, alpha[eid[start + j]]);
#pragma unroll
    for (int off = 32; off; off >>= 1) m = fmaxf(m, __shfl_xor(m, off));

    constexpr int V = DOUT / 64;
    float acc[V];
    float denom;
    {
        float w = expf(aself - m);
        denom = w;
        const float* h = H + (size_t)wid * DOUT;
#pragma unroll
        for (int v = 0; v < V; v++) acc[v] = w * h[lane * V + v];
    }
    for (int j = 0; j < d; j++) {
        int e = eid[start + j];
        float w = expf(alpha[e] - m);
        denom += w;
        const float* h = H + (size_t)src[e] * DOUT;
#pragma unroll
        for (int v = 0; v < V; v++) acc[v] = fmaf(w, h[lane * V + v], acc[v]);
    }
    float inv = 1.0f / (denom + 1e-16f);
#pragma unroll
    for (int v = 0; v < V; v++) {
        float o = acc[v] * inv + bias[lane * V + v];
        if (RELU) o = fmaxf(o, 0.f);
        out[(size_t)wid * DOUT + lane * V + v] = o;
    }
}

// ---------- launch ----------

extern "C" void kernel_launch(void* const* d_in, const int* in_sizes, int n_in,
                              void* d_out, int out_size, void* d_ws, size_t ws_size,
                              hipStream_t stream) {
    const float* x     = (const float*)d_in[0];
    const int*   eidx  = (const int*)d_in[1];
    const float* eattr = (const float*)d_in[2];
    const int N = in_sizes[0] / 128;
    const int E = in_sizes[1] / 2;
    const int* src = eidx;
    const int* dst = eidx + E;

    char* ws = (char*)d_ws;
    size_t off = 0;
    auto alloc = [&](size_t bytes) -> void* {
        void* p = ws + off;
        off += (bytes + 255) & ~(size_t)255;
        return p;
    };
    float* bufA      = (float*)alloc((size_t)N * 128 * sizeof(float));
    float* hbuf      = (float*)alloc((size_t)N * 128 * sizeof(float));
    float* mean_attr = (float*)alloc((size_t)N * 8 * sizeof(float));
    int*   deg       = (int*)alloc((size_t)N * sizeof(int));
    int*   rowstart  = (int*)alloc((size_t)N * sizeof(int));
    int*   cursor    = (int*)alloc((size_t)N * sizeof(int));
    float* hs        = (float*)alloc((size_t)N * sizeof(float));
    float* hd        = (float*)alloc((size_t)N * sizeof(float));
    float* alpha     = (float*)alloc((size_t)(E + N) * sizeof(float));
    int*   eid       = (int*)alloc((size_t)E * sizeof(int));
    float* wea       = (float*)alloc(64 * sizeof(float));
    int*   partials  = (int*)alloc(256 * sizeof(int));

    const int tb = 256;
    hipMemsetAsync(deg, 0, (size_t)N * sizeof(int), stream);

    // CSR build (int atomics only), then CSR-based self-loop mean (no float atomics)
    k_count<<<(E + tb - 1) / tb, tb, 0, stream>>>(dst, deg, E);
    int nb = (N + 255) / 256;
    k_scan_block<<<nb, 256, 0, stream>>>(deg, rowstart, partials, N);
    k_scan_partials<<<1, 256, 0, stream>>>(partials, nb);
    k_add_offsets<<<nb, 256, 0, stream>>>(rowstart, cursor, partials, N);
    k_fill_csr<<<(E + tb - 1) / tb, tb, 0, stream>>>(dst, cursor, eid, E);
    int nwave_blocks = (N * 64 + tb - 1) / tb;
    k_mean_csr<<<nwave_blocks, tb, 0, stream>>>(eattr, rowstart, deg, eid, mean_attr, N);

    // ---- layer 0 (128->128, relu) ----
    {
        const float* W   = (const float*)d_in[3];
        const float* as_ = (const float*)d_in[4];
        const float* ad_ = (const float*)d_in[5];
        const float* We  = (const float*)d_in[6];
        const float* ae  = (const float*)d_in[7];
        const float* b   = (const float*)d_in[8];
        k_gemm_dots<128, 128><<<(N + 31) / 32, 256, 0, stream>>>(x, W, as_, ad_, hbuf, hs, hd, N);
        k_wea<128><<<1, 64, 0, stream>>>(We, ae, wea);
        k_edge_alpha<<<(E + N + tb - 1) / tb, tb, 0, stream>>>(src, dst, eattr, mean_attr, hs, hd, wea, alpha, E, N);
        k_aggregate<128, true><<<nwave_blocks, tb, 0, stream>>>(hbuf, rowstart, deg, eid, src, alpha, alpha + E, b, bufA, N);
    }
    // ---- layer 1 (128->128, relu) ----
    {
        const float* W   = (const float*)d_in[9];
        const float* as_ = (const float*)d_in[10];
        const float* ad_ = (const float*)d_in[11];
        const float* We  = (const float*)d_in[12];
        const float* ae  = (const float*)d_in[13];
        const float* b   = (const float*)d_in[14];
        k_gemm_dots<128, 128><<<(N + 31) / 32, 256, 0, stream>>>(bufA, W, as_, ad_, hbuf, hs, hd, N);
        k_wea<128><<<1, 64, 0, stream>>>(We, ae, wea);
        k_edge_alpha<<<(E + N + tb - 1) / tb, tb, 0, stream>>>(src, dst, eattr, mean_attr, hs, hd, wea, alpha, E, N);
        k_aggregate<128, true><<<nwave_blocks, tb, 0, stream>>>(hbuf, rowstart, deg, eid, src, alpha, alpha + E, b, bufA, N);
    }
    // ---- layer 2 (128->64, no relu) ----
    {
        const float* W   = (const float*)d_in[15];
        const float* as_ = (const float*)d_in[16];
        const float* ad_ = (const float*)d_in[17];
        const float* We  = (const float*)d_in[18];
        const float* ae  = (const float*)d_in[19];
        const float* b   = (const float*)d_in[20];
        k_gemm_dots<128, 64><<<(N + 63) / 64, 256, 0, stream>>>(bufA, W, as_, ad_, hbuf, hs, hd, N);
        k_wea<64><<<1, 64, 0, stream>>>(We, ae, wea);
        k_edge_alpha<<<(E + N + tb - 1) / tb, tb, 0, stream>>>(src, dst, eattr, mean_attr, hs, hd, wea, alpha, E, N);
        k_aggregate<64, false><<<nwave_blocks, tb, 0, stream>>>(hbuf, rowstart, deg, eid, src, alpha, alpha + E, b, (float*)d_out, N);
    }
}

// Round 3
// 536.007 us; speedup vs baseline: 2.1110x; 1.0284x over previous
//
#include <hip/hip_runtime.h>
#include <hip/hip_fp16.h>
#include <cstdint>

#define NEG_SLOPE 0.2f

// ---------- preprocessing ----------

__global__ void k_count(const int* __restrict__ dst, int* __restrict__ deg, int E) {
    int e = blockIdx.x * blockDim.x + threadIdx.x;
    if (e < E) atomicAdd(deg + dst[e], 1);
}

__global__ void k_scan_block(const int* __restrict__ in, int* __restrict__ out,
                             int* __restrict__ partials, int n) {
    __shared__ int s[256];
    int i = blockIdx.x * 256 + threadIdx.x;
    int v = (i < n) ? in[i] : 0;
    s[threadIdx.x] = v;
    __syncthreads();
    for (int off = 1; off < 256; off <<= 1) {
        int t = (threadIdx.x >= off) ? s[threadIdx.x - off] : 0;
        __syncthreads();
        s[threadIdx.x] += t;
        __syncthreads();
    }
    if (i < n) out[i] = s[threadIdx.x] - v;   // exclusive
    if (threadIdx.x == 255) partials[blockIdx.x] = s[255];
}

__global__ void k_scan_partials(int* __restrict__ partials, int nb) {
    __shared__ int s[256];
    int v = (threadIdx.x < nb) ? partials[threadIdx.x] : 0;
    s[threadIdx.x] = v;
    __syncthreads();
    for (int off = 1; off < 256; off <<= 1) {
        int t = (threadIdx.x >= off) ? s[threadIdx.x - off] : 0;
        __syncthreads();
        s[threadIdx.x] += t;
        __syncthreads();
    }
    if (threadIdx.x < nb) partials[threadIdx.x] = s[threadIdx.x] - v;  // exclusive
}

__global__ void k_add_offsets(int* __restrict__ rowstart, int* __restrict__ cursor,
                              const int* __restrict__ partials, int n) {
    int i = blockIdx.x * 256 + threadIdx.x;
    if (i >= n) return;
    int r = rowstart[i] + partials[blockIdx.x];
    rowstart[i] = r;
    cursor[i] = r;
}

__global__ void k_fill_csr(const int* __restrict__ dst, int* __restrict__ cursor,
                           int* __restrict__ eid, int E) {
    int e = blockIdx.x * blockDim.x + threadIdx.x;
    if (e >= E) return;
    int pos = atomicAdd(cursor + dst[e], 1);
    eid[pos] = e;
}

// wave per node: lanes (j0*8+k) sum attr k of edges j0, j0+8, ... then reduce
__global__ void k_mean_csr(const float* __restrict__ ea, const int* __restrict__ rowstart,
                           const int* __restrict__ deg, const int* __restrict__ eid,
                           float* __restrict__ mean_attr, int n) {
    int t = blockIdx.x * blockDim.x + threadIdx.x;
    int wid = t >> 6, lane = t & 63;
    if (wid >= n) return;
    int start = rowstart[wid], d = deg[wid];
    int j0 = lane >> 3, k = lane & 7;
    float s = 0.f;
    for (int j = j0; j < d; j += 8) s += ea[(size_t)eid[start + j] * 8 + k];
    s += __shfl_xor(s, 8);
    s += __shfl_xor(s, 16);
    s += __shfl_xor(s, 32);
    if (lane < 8) {
        int dd = d < 1 ? 1 : d;
        mean_attr[(size_t)wid * 8 + lane] = s / (float)dd;
    }
}

// ---------- fused GEMM + attention dots (fp16 H output) ----------

template<int DIN, int DOUT>
__global__ __launch_bounds__(256) void k_gemm_dots(
    const float* __restrict__ X, const float* __restrict__ W,
    const float* __restrict__ as_, const float* __restrict__ ad_,
    __half* __restrict__ H, float* __restrict__ hs, float* __restrict__ hd, int n)
{
    constexpr int GROUP = DOUT / 4;     // threads per row-quad (32 or 16)
    constexpr int BM = 1024 / GROUP;    // rows per block (32 or 64)
    __shared__ float sW[DIN * DOUT];
    __shared__ float sX[BM * DIN];

    int tid = threadIdx.x;
    int row_base = blockIdx.x * BM;

    { // load W as float4
        constexpr int WV = DIN * DOUT / 4;
        const float4* Wv = (const float4*)W;
        float4* sWv = (float4*)sW;
#pragma unroll
        for (int i = tid; i < WV; i += 256) sWv[i] = Wv[i];
    }
    { // load X tile as float4 (guard tail rows)
        int rows_avail = n - row_base; if (rows_avail > BM) rows_avail = BM;
        int xlim = rows_avail * DIN / 4;
        const float4* Xv = (const float4*)(X + (size_t)row_base * DIN);
        float4* sXv = (float4*)sX;
        for (int i = tid; i < xlim; i += 256) sXv[i] = Xv[i];
    }
    __syncthreads();

    int r0 = (tid / GROUP) * 4;
    int c0 = (tid % GROUP) * 4;

    float acc[4][4] = {};
#pragma unroll 4
    for (int k = 0; k < DIN; k++) {
        float4 w = *(const float4*)&sW[k * DOUT + c0];
        float xv[4];
#pragma unroll
        for (int i = 0; i < 4; i++) xv[i] = sX[(r0 + i) * DIN + k];
#pragma unroll
        for (int i = 0; i < 4; i++) {
            acc[i][0] = fmaf(xv[i], w.x, acc[i][0]);
            acc[i][1] = fmaf(xv[i], w.y, acc[i][1]);
            acc[i][2] = fmaf(xv[i], w.z, acc[i][2]);
            acc[i][3] = fmaf(xv[i], w.w, acc[i][3]);
        }
    }

    float4 av = *(const float4*)&as_[c0];
    float4 dv = *(const float4*)&ad_[c0];

#pragma unroll
    for (int i = 0; i < 4; i++) {
        int row = row_base + r0 + i;
        bool ok = row < n;
        if (ok) {
            __half2 p0 = __floats2half2_rn(acc[i][0], acc[i][1]);
            __half2 p1 = __floats2half2_rn(acc[i][2], acc[i][3]);
            __half2* dst2 = (__half2*)&H[(size_t)row * DOUT + c0];
            dst2[0] = p0;
            dst2[1] = p1;
        }
        float ps = acc[i][0] * av.x + acc[i][1] * av.y + acc[i][2] * av.z + acc[i][3] * av.w;
        float pd = acc[i][0] * dv.x + acc[i][1] * dv.y + acc[i][2] * dv.z + acc[i][3] * dv.w;
#pragma unroll
        for (int off = GROUP / 2; off; off >>= 1) {
            ps += __shfl_xor(ps, off);
            pd += __shfl_xor(pd, off);
        }
        if (ok && (tid % GROUP) == 0) { hs[row] = ps; hd[row] = pd; }
    }
}

// ---------- per-layer edge/aggregate kernels ----------

// one launch computes wea[layer][k] = sum_k We[layer][k*D..] . ae[layer]
__global__ void k_wea_all(const float* __restrict__ We0, const float* __restrict__ ae0,
                          const float* __restrict__ We1, const float* __restrict__ ae1,
                          const float* __restrict__ We2, const float* __restrict__ ae2,
                          float* __restrict__ wea) {
    int j = threadIdx.x;
    if (j >= 24) return;
    int layer = j >> 3, k = j & 7;
    const float* We = layer == 0 ? We0 : (layer == 1 ? We1 : We2);
    const float* ae = layer == 0 ? ae0 : (layer == 1 ? ae1 : ae2);
    int D = layer == 2 ? 64 : 128;
    float s = 0.f;
    for (int t = 0; t < D; t++) s = fmaf(We[(size_t)k * D + t], ae[t], s);
    wea[j] = s;
}

__global__ void k_edge_alpha(const int* __restrict__ src, const int* __restrict__ dst,
                             const float* __restrict__ ea, const float* __restrict__ mean_attr,
                             const float* __restrict__ hs, const float* __restrict__ hd,
                             const float* __restrict__ wea, float* __restrict__ alpha,
                             int E, int n) {
    int e = blockIdx.x * blockDim.x + threadIdx.x;
    if (e >= E + n) return;
    int s, d;
    const float* a;
    if (e < E) { s = src[e]; d = dst[e]; a = ea + (size_t)e * 8; }
    else       { s = e - E;  d = s;      a = mean_attr + (size_t)s * 8; }
    float4 a0 = *(const float4*)a;
    float4 a1 = *(const float4*)(a + 4);
    float4 w0 = *(const float4*)wea;
    float4 w1 = *(const float4*)(wea + 4);
    float al = hs[s] + hd[d];
    al = fmaf(a0.x, w0.x, al); al = fmaf(a0.y, w0.y, al);
    al = fmaf(a0.z, w0.z, al); al = fmaf(a0.w, w0.w, al);
    al = fmaf(a1.x, w1.x, al); al = fmaf(a1.y, w1.y, al);
    al = fmaf(a1.z, w1.z, al); al = fmaf(a1.w, w1.w, al);
    alpha[e] = al > 0.f ? al : NEG_SLOPE * al;
}

template<int DOUT, bool RELU>
__global__ void k_aggregate(const __half* __restrict__ H, const int* __restrict__ rowstart,
                            const int* __restrict__ deg, const int* __restrict__ eid,
                            const int* __restrict__ src, const float* __restrict__ alpha,
                            const float* __restrict__ alpha_self, const float* __restrict__ bias,
                            float* __restrict__ out, int n) {
    int t = blockIdx.x * blockDim.x + threadIdx.x;
    int wid = t >> 6, lane = t & 63;
    if (wid >= n) return;
    int start = rowstart[wid], d = deg[wid];
    float aself = alpha_self[wid];

    float m = aself;
    for (int j = lane; j < d; j += 64) m = fmaxf(m, alpha[eid[start + j]]);
#pragma unroll
    for (int off = 32; off; off >>= 1) m = fmaxf(m, __shfl_xor(m, off));

    constexpr int V = DOUT / 64;
    float acc[V];
    float denom;
    {
        float w = expf(aself - m);
        denom = w;
        if constexpr (V == 2) {
            float2 f = __half22float2(((const __half2*)(H + (size_t)wid * DOUT))[lane]);
            acc[0] = w * f.x; acc[1] = w * f.y;
        } else {
            acc[0] = w * __half2float(H[(size_t)wid * DOUT + lane]);
        }
    }
    for (int j = 0; j < d; j++) {
        int e = eid[start + j];
        float w = expf(alpha[e] - m);
        denom += w;
        const __half* h = H + (size_t)src[e] * DOUT;
        if constexpr (V == 2) {
            float2 f = __half22float2(((const __half2*)h)[lane]);
            acc[0] = fmaf(w, f.x, acc[0]);
            acc[1] = fmaf(w, f.y, acc[1]);
        } else {
            acc[0] = fmaf(w, __half2float(h[lane]), acc[0]);
        }
    }
    float inv = 1.0f / (denom + 1e-16f);
#pragma unroll
    for (int v = 0; v < V; v++) {
        float o = acc[v] * inv + bias[lane * V + v];
        if (RELU) o = fmaxf(o, 0.f);
        out[(size_t)wid * DOUT + lane * V + v] = o;
    }
}

// ---------- launch ----------

extern "C" void kernel_launch(void* const* d_in, const int* in_sizes, int n_in,
                              void* d_out, int out_size, void* d_ws, size_t ws_size,
                              hipStream_t stream) {
    const float* x     = (const float*)d_in[0];
    const int*   eidx  = (const int*)d_in[1];
    const float* eattr = (const float*)d_in[2];
    const int N = in_sizes[0] / 128;
    const int E = in_sizes[1] / 2;
    const int* src = eidx;
    const int* dst = eidx + E;

    char* ws = (char*)d_ws;
    size_t off = 0;
    auto alloc = [&](size_t bytes) -> void* {
        void* p = ws + off;
        off += (bytes + 255) & ~(size_t)255;
        return p;
    };
    float*  bufA      = (float*)alloc((size_t)N * 128 * sizeof(float));
    __half* hbuf      = (__half*)alloc((size_t)N * 128 * sizeof(__half));
    float*  mean_attr = (float*)alloc((size_t)N * 8 * sizeof(float));
    int*    deg       = (int*)alloc((size_t)N * sizeof(int));
    int*    rowstart  = (int*)alloc((size_t)N * sizeof(int));
    int*    cursor    = (int*)alloc((size_t)N * sizeof(int));
    float*  hs        = (float*)alloc((size_t)N * sizeof(float));
    float*  hd        = (float*)alloc((size_t)N * sizeof(float));
    float*  alpha     = (float*)alloc((size_t)(E + N) * sizeof(float));
    int*    eid       = (int*)alloc((size_t)E * sizeof(int));
    float*  wea       = (float*)alloc(64 * sizeof(float));
    int*    partials  = (int*)alloc(256 * sizeof(int));

    const int tb = 256;
    hipMemsetAsync(deg, 0, (size_t)N * sizeof(int), stream);

    // CSR build (int atomics only), then CSR-based self-loop mean (no float atomics)
    k_count<<<(E + tb - 1) / tb, tb, 0, stream>>>(dst, deg, E);
    int nb = (N + 255) / 256;
    k_scan_block<<<nb, 256, 0, stream>>>(deg, rowstart, partials, N);
    k_scan_partials<<<1, 256, 0, stream>>>(partials, nb);
    k_add_offsets<<<nb, 256, 0, stream>>>(rowstart, cursor, partials, N);
    k_fill_csr<<<(E + tb - 1) / tb, tb, 0, stream>>>(dst, cursor, eid, E);
    int nwave_blocks = (N * 64 + tb - 1) / tb;
    k_mean_csr<<<nwave_blocks, tb, 0, stream>>>(eattr, rowstart, deg, eid, mean_attr, N);
    k_wea_all<<<1, 64, 0, stream>>>((const float*)d_in[6], (const float*)d_in[7],
                                    (const float*)d_in[12], (const float*)d_in[13],
                                    (const float*)d_in[18], (const float*)d_in[19], wea);

    // ---- layer 0 (128->128, relu) ----
    {
        const float* W   = (const float*)d_in[3];
        const float* as_ = (const float*)d_in[4];
        const float* ad_ = (const float*)d_in[5];
        const float* b   = (const float*)d_in[8];
        k_gemm_dots<128, 128><<<(N + 31) / 32, 256, 0, stream>>>(x, W, as_, ad_, hbuf, hs, hd, N);
        k_edge_alpha<<<(E + N + tb - 1) / tb, tb, 0, stream>>>(src, dst, eattr, mean_attr, hs, hd, wea, alpha, E, N);
        k_aggregate<128, true><<<nwave_blocks, tb, 0, stream>>>(hbuf, rowstart, deg, eid, src, alpha, alpha + E, b, bufA, N);
    }
    // ---- layer 1 (128->128, relu) ----
    {
        const float* W   = (const float*)d_in[9];
        const float* as_ = (const float*)d_in[10];
        const float* ad_ = (const float*)d_in[11];
        const float* b   = (const float*)d_in[14];
        k_gemm_dots<128, 128><<<(N + 31) / 32, 256, 0, stream>>>(bufA, W, as_, ad_, hbuf, hs, hd, N);
        k_edge_alpha<<<(E + N + tb - 1) / tb, tb, 0, stream>>>(src, dst, eattr, mean_attr, hs, hd, wea + 8, alpha, E, N);
        k_aggregate<128, true><<<nwave_blocks, tb, 0, stream>>>(hbuf, rowstart, deg, eid, src, alpha, alpha + E, b, bufA, N);
    }
    // ---- layer 2 (128->64, no relu) ----
    {
        const float* W   = (const float*)d_in[15];
        const float* as_ = (const float*)d_in[16];
        const float* ad_ = (const float*)d_in[17];
        const float* b   = (const float*)d_in[20];
        k_gemm_dots<128, 64><<<(N + 63) / 64, 256, 0, stream>>>(bufA, W, as_, ad_, hbuf, hs, hd, N);
        k_edge_alpha<<<(E + N + tb - 1) / tb, tb, 0, stream>>>(src, dst, eattr, mean_attr, hs, hd, wea + 16, alpha, E, N);
        k_aggregate<64, false><<<nwave_blocks, tb, 0, stream>>>(hbuf, rowstart, deg, eid, src, alpha, alpha + E, b, (float*)d_out, N);
    }
}

// Round 4
// 406.344 us; speedup vs baseline: 2.7846x; 1.3191x over previous
//
#include <hip/hip_runtime.h>
#include <hip/hip_fp16.h>
#include <cstdint>

#define NEG_SLOPE 0.2f

// ---------- preprocessing ----------

__global__ void k_count(const int* __restrict__ dst, int* __restrict__ deg, int E) {
    int e = blockIdx.x * blockDim.x + threadIdx.x;
    if (e < E) atomicAdd(deg + dst[e], 1);
}

__global__ void k_scan_block(const int* __restrict__ in, int* __restrict__ out,
                             int* __restrict__ partials, int n) {
    __shared__ int s[256];
    int i = blockIdx.x * 256 + threadIdx.x;
    int v = (i < n) ? in[i] : 0;
    s[threadIdx.x] = v;
    __syncthreads();
    for (int off = 1; off < 256; off <<= 1) {
        int t = (threadIdx.x >= off) ? s[threadIdx.x - off] : 0;
        __syncthreads();
        s[threadIdx.x] += t;
        __syncthreads();
    }
    if (i < n) out[i] = s[threadIdx.x] - v;   // exclusive
    if (threadIdx.x == 255) partials[blockIdx.x] = s[255];
}

__global__ void k_scan_partials(int* __restrict__ partials, int nb) {
    __shared__ int s[256];
    int v = (threadIdx.x < nb) ? partials[threadIdx.x] : 0;
    s[threadIdx.x] = v;
    __syncthreads();
    for (int off = 1; off < 256; off <<= 1) {
        int t = (threadIdx.x >= off) ? s[threadIdx.x - off] : 0;
        __syncthreads();
        s[threadIdx.x] += t;
        __syncthreads();
    }
    if (threadIdx.x < nb) partials[threadIdx.x] = s[threadIdx.x] - v;  // exclusive
}

__global__ void k_add_offsets(int* __restrict__ rowstart, int* __restrict__ cursor,
                              const int* __restrict__ partials, int n) {
    int i = blockIdx.x * 256 + threadIdx.x;
    if (i >= n) return;
    int r = rowstart[i] + partials[blockIdx.x];
    rowstart[i] = r;
    cursor[i] = r;
}

__global__ void k_fill_csr(const int* __restrict__ src, const int* __restrict__ dst,
                           int* __restrict__ cursor, int* __restrict__ eid,
                           int* __restrict__ src_csr, int* __restrict__ inv, int E) {
    int e = blockIdx.x * blockDim.x + threadIdx.x;
    if (e >= E) return;
    int pos = atomicAdd(cursor + dst[e], 1);
    eid[pos] = e;
    src_csr[pos] = src[e];
    inv[e] = pos;
}

// wave per node: lanes (j0*8+k) sum attr k of edges j0, j0+8, ... then reduce
__global__ void k_mean_csr(const float* __restrict__ ea, const int* __restrict__ rowstart,
                           const int* __restrict__ deg, const int* __restrict__ eid,
                           float* __restrict__ mean_attr, int n) {
    int t = blockIdx.x * blockDim.x + threadIdx.x;
    int wid = t >> 6, lane = t & 63;
    if (wid >= n) return;
    int start = rowstart[wid], d = deg[wid];
    int j0 = lane >> 3, k = lane & 7;
    float s = 0.f;
    for (int j = j0; j < d; j += 8) s += ea[(size_t)eid[start + j] * 8 + k];
    s += __shfl_xor(s, 8);
    s += __shfl_xor(s, 16);
    s += __shfl_xor(s, 32);
    if (lane < 8) {
        int dd = d < 1 ? 1 : d;
        mean_attr[(size_t)wid * 8 + lane] = s / (float)dd;
    }
}

// ---------- fused GEMM + attention dots (fp16 H output) ----------

template<int DIN, int DOUT>
__global__ __launch_bounds__(256) void k_gemm_dots(
    const float* __restrict__ X, const float* __restrict__ W,
    const float* __restrict__ as_, const float* __restrict__ ad_,
    __half* __restrict__ H, float* __restrict__ hs, float* __restrict__ hd, int n)
{
    constexpr int GROUP = DOUT / 4;     // threads per row-quad (32 or 16)
    constexpr int BM = 1024 / GROUP;    // rows per block (32 or 64)
    __shared__ float sW[DIN * DOUT];
    __shared__ float sX[BM * DIN];

    int tid = threadIdx.x;
    int row_base = blockIdx.x * BM;

    { // load W as float4
        constexpr int WV = DIN * DOUT / 4;
        const float4* Wv = (const float4*)W;
        float4* sWv = (float4*)sW;
#pragma unroll
        for (int i = tid; i < WV; i += 256) sWv[i] = Wv[i];
    }
    { // load X tile as float4 (guard tail rows)
        int rows_avail = n - row_base; if (rows_avail > BM) rows_avail = BM;
        int xlim = rows_avail * DIN / 4;
        const float4* Xv = (const float4*)(X + (size_t)row_base * DIN);
        float4* sXv = (float4*)sX;
        for (int i = tid; i < xlim; i += 256) sXv[i] = Xv[i];
    }
    __syncthreads();

    int r0 = (tid / GROUP) * 4;
    int c0 = (tid % GROUP) * 4;

    float acc[4][4] = {};
#pragma unroll 4
    for (int k = 0; k < DIN; k++) {
        float4 w = *(const float4*)&sW[k * DOUT + c0];
        float xv[4];
#pragma unroll
        for (int i = 0; i < 4; i++) xv[i] = sX[(r0 + i) * DIN + k];
#pragma unroll
        for (int i = 0; i < 4; i++) {
            acc[i][0] = fmaf(xv[i], w.x, acc[i][0]);
            acc[i][1] = fmaf(xv[i], w.y, acc[i][1]);
            acc[i][2] = fmaf(xv[i], w.z, acc[i][2]);
            acc[i][3] = fmaf(xv[i], w.w, acc[i][3]);
        }
    }

    float4 av = *(const float4*)&as_[c0];
    float4 dv = *(const float4*)&ad_[c0];

#pragma unroll
    for (int i = 0; i < 4; i++) {
        int row = row_base + r0 + i;
        bool ok = row < n;
        if (ok) {
            __half2 p0 = __floats2half2_rn(acc[i][0], acc[i][1]);
            __half2 p1 = __floats2half2_rn(acc[i][2], acc[i][3]);
            __half2* dst2 = (__half2*)&H[(size_t)row * DOUT + c0];
            dst2[0] = p0;
            dst2[1] = p1;
        }
        float ps = acc[i][0] * av.x + acc[i][1] * av.y + acc[i][2] * av.z + acc[i][3] * av.w;
        float pd = acc[i][0] * dv.x + acc[i][1] * dv.y + acc[i][2] * dv.z + acc[i][3] * dv.w;
#pragma unroll
        for (int off = GROUP / 2; off; off >>= 1) {
            ps += __shfl_xor(ps, off);
            pd += __shfl_xor(pd, off);
        }
        if (ok && (tid % GROUP) == 0) { hs[row] = ps; hd[row] = pd; }
    }
}

// ---------- per-layer edge/aggregate kernels ----------

__global__ void k_wea_all(const float* __restrict__ We0, const float* __restrict__ ae0,
                          const float* __restrict__ We1, const float* __restrict__ ae1,
                          const float* __restrict__ We2, const float* __restrict__ ae2,
                          float* __restrict__ wea) {
    int j = threadIdx.x;
    if (j >= 24) return;
    int layer = j >> 3, k = j & 7;
    const float* We = layer == 0 ? We0 : (layer == 1 ? We1 : We2);
    const float* ae = layer == 0 ? ae0 : (layer == 1 ? ae1 : ae2);
    int D = layer == 2 ? 64 : 128;
    float s = 0.f;
    for (int t = 0; t < D; t++) s = fmaf(We[(size_t)k * D + t], ae[t], s);
    wea[j] = s;
}

// alpha written directly in CSR order via inv[]; self-loop alpha to dense array
__global__ void k_edge_alpha(const int* __restrict__ src, const int* __restrict__ dst,
                             const float* __restrict__ ea, const float* __restrict__ mean_attr,
                             const float* __restrict__ hs, const float* __restrict__ hd,
                             const float* __restrict__ wea, const int* __restrict__ inv,
                             float* __restrict__ alpha_csr, float* __restrict__ alpha_self,
                             int E, int n) {
    int e = blockIdx.x * blockDim.x + threadIdx.x;
    if (e >= E + n) return;
    int s, d;
    const float* a;
    if (e < E) { s = src[e]; d = dst[e]; a = ea + (size_t)e * 8; }
    else       { s = e - E;  d = s;      a = mean_attr + (size_t)s * 8; }
    float4 a0 = *(const float4*)a;
    float4 a1 = *(const float4*)(a + 4);
    float4 w0 = *(const float4*)wea;
    float4 w1 = *(const float4*)(wea + 4);
    float al = hs[s] + hd[d];
    al = fmaf(a0.x, w0.x, al); al = fmaf(a0.y, w0.y, al);
    al = fmaf(a0.z, w0.z, al); al = fmaf(a0.w, w0.w, al);
    al = fmaf(a1.x, w1.x, al); al = fmaf(a1.y, w1.y, al);
    al = fmaf(a1.z, w1.z, al); al = fmaf(a1.w, w1.w, al);
    al = al > 0.f ? al : NEG_SLOPE * al;
    if (e < E) alpha_csr[inv[e]] = al;
    else       alpha_self[e - E] = al;
}

// wave per node; per-64-edge chunk: coalesced alpha/src loads, lane-parallel exp,
// wave-reduced denom, then shfl-broadcast gather loop (addresses register-resident).
template<int DOUT, bool RELU>
__global__ void k_aggregate(const __half* __restrict__ H, const int* __restrict__ rowstart,
                            const int* __restrict__ deg, const int* __restrict__ src_csr,
                            const float* __restrict__ alpha_csr,
                            const float* __restrict__ alpha_self, const float* __restrict__ bias,
                            float* __restrict__ out, int n) {
    int t = blockIdx.x * blockDim.x + threadIdx.x;
    int wid = t >> 6, lane = t & 63;
    if (wid >= n) return;
    int start = rowstart[wid], d = deg[wid];
    float aself = alpha_self[wid];

    // pass 1: segment max (coalesced alpha reads)
    float m = aself;
    for (int j = lane; j < d; j += 64) m = fmaxf(m, alpha_csr[start + j]);
#pragma unroll
    for (int off = 32; off; off >>= 1) m = fmaxf(m, __shfl_xor(m, off));

    constexpr int V = DOUT / 64;
    float acc[V];
    float denom;
    {
        float w = expf(aself - m);
        denom = w;
        const __half* h = H + (size_t)wid * DOUT;
        if constexpr (V == 2) {
            float2 f = __half22float2(((const __half2*)h)[lane]);
            acc[0] = w * f.x; acc[1] = w * f.y;
        } else {
            acc[0] = w * __half2float(h[lane]);
        }
    }

    for (int base = 0; base < d; base += 64) {
        int rem = d - base; if (rem > 64) rem = 64;
        float a = -3.0e38f;
        int s = 0;
        if (lane < rem) {
            a = alpha_csr[start + base + lane];
            s = src_csr[start + base + lane];
        }
        float ex = expf(a - m);                 // masked lanes -> 0
        float exs = ex;
#pragma unroll
        for (int off = 32; off; off >>= 1) exs += __shfl_xor(exs, off);
        denom += exs;

#pragma unroll 4
        for (int j = 0; j < rem; j++) {
            float w = __shfl(ex, j);
            int sj = __shfl(s, j);
            const __half* h = H + (size_t)sj * DOUT;
            if constexpr (V == 2) {
                float2 f = __half22float2(((const __half2*)h)[lane]);
                acc[0] = fmaf(w, f.x, acc[0]);
                acc[1] = fmaf(w, f.y, acc[1]);
            } else {
                acc[0] = fmaf(w, __half2float(h[lane]), acc[0]);
            }
        }
    }

    float inv = 1.0f / (denom + 1e-16f);
#pragma unroll
    for (int v = 0; v < V; v++) {
        float o = acc[v] * inv + bias[lane * V + v];
        if (RELU) o = fmaxf(o, 0.f);
        out[(size_t)wid * DOUT + lane * V + v] = o;
    }
}

// ---------- launch ----------

extern "C" void kernel_launch(void* const* d_in, const int* in_sizes, int n_in,
                              void* d_out, int out_size, void* d_ws, size_t ws_size,
                              hipStream_t stream) {
    const float* x     = (const float*)d_in[0];
    const int*   eidx  = (const int*)d_in[1];
    const float* eattr = (const float*)d_in[2];
    const int N = in_sizes[0] / 128;
    const int E = in_sizes[1] / 2;
    const int* src = eidx;
    const int* dst = eidx + E;

    char* ws = (char*)d_ws;
    size_t off = 0;
    auto alloc = [&](size_t bytes) -> void* {
        void* p = ws + off;
        off += (bytes + 255) & ~(size_t)255;
        return p;
    };
    float*  bufA      = (float*)alloc((size_t)N * 128 * sizeof(float));
    __half* hbuf      = (__half*)alloc((size_t)N * 128 * sizeof(__half));
    float*  mean_attr = (float*)alloc((size_t)N * 8 * sizeof(float));
    int*    deg       = (int*)alloc((size_t)N * sizeof(int));
    int*    rowstart  = (int*)alloc((size_t)N * sizeof(int));
    int*    cursor    = (int*)alloc((size_t)N * sizeof(int));
    float*  hs        = (float*)alloc((size_t)N * sizeof(float));
    float*  hd        = (float*)alloc((size_t)N * sizeof(float));
    float*  alpha_csr = (float*)alloc((size_t)E * sizeof(float));
    float*  alpha_self= (float*)alloc((size_t)N * sizeof(float));
    int*    eid       = (int*)alloc((size_t)E * sizeof(int));
    int*    src_csr   = (int*)alloc((size_t)E * sizeof(int));
    int*    invp      = (int*)alloc((size_t)E * sizeof(int));
    float*  wea       = (float*)alloc(64 * sizeof(float));
    int*    partials  = (int*)alloc(256 * sizeof(int));

    const int tb = 256;
    hipMemsetAsync(deg, 0, (size_t)N * sizeof(int), stream);

    k_count<<<(E + tb - 1) / tb, tb, 0, stream>>>(dst, deg, E);
    int nb = (N + 255) / 256;
    k_scan_block<<<nb, 256, 0, stream>>>(deg, rowstart, partials, N);
    k_scan_partials<<<1, 256, 0, stream>>>(partials, nb);
    k_add_offsets<<<nb, 256, 0, stream>>>(rowstart, cursor, partials, N);
    k_fill_csr<<<(E + tb - 1) / tb, tb, 0, stream>>>(src, dst, cursor, eid, src_csr, invp, E);
    int nwave_blocks = (N * 64 + tb - 1) / tb;
    k_mean_csr<<<nwave_blocks, tb, 0, stream>>>(eattr, rowstart, deg, eid, mean_attr, N);
    k_wea_all<<<1, 64, 0, stream>>>((const float*)d_in[6], (const float*)d_in[7],
                                    (const float*)d_in[12], (const float*)d_in[13],
                                    (const float*)d_in[18], (const float*)d_in[19], wea);

    // ---- layer 0 (128->128, relu) ----
    {
        const float* W   = (const float*)d_in[3];
        const float* as_ = (const float*)d_in[4];
        const float* ad_ = (const float*)d_in[5];
        const float* b   = (const float*)d_in[8];
        k_gemm_dots<128, 128><<<(N + 31) / 32, 256, 0, stream>>>(x, W, as_, ad_, hbuf, hs, hd, N);
        k_edge_alpha<<<(E + N + tb - 1) / tb, tb, 0, stream>>>(src, dst, eattr, mean_attr, hs, hd, wea, invp, alpha_csr, alpha_self, E, N);
        k_aggregate<128, true><<<nwave_blocks, tb, 0, stream>>>(hbuf, rowstart, deg, src_csr, alpha_csr, alpha_self, b, bufA, N);
    }
    // ---- layer 1 (128->128, relu) ----
    {
        const float* W   = (const float*)d_in[9];
        const float* as_ = (const float*)d_in[10];
        const float* ad_ = (const float*)d_in[11];
        const float* b   = (const float*)d_in[14];
        k_gemm_dots<128, 128><<<(N + 31) / 32, 256, 0, stream>>>(bufA, W, as_, ad_, hbuf, hs, hd, N);
        k_edge_alpha<<<(E + N + tb - 1) / tb, tb, 0, stream>>>(src, dst, eattr, mean_attr, hs, hd, wea + 8, invp, alpha_csr, alpha_self, E, N);
        k_aggregate<128, true><<<nwave_blocks, tb, 0, stream>>>(hbuf, rowstart, deg, src_csr, alpha_csr, alpha_self, b, bufA, N);
    }
    // ---- layer 2 (128->64, no relu) ----
    {
        const float* W   = (const float*)d_in[15];
        const float* as_ = (const float*)d_in[16];
        const float* ad_ = (const float*)d_in[17];
        const float* b   = (const float*)d_in[20];
        k_gemm_dots<128, 64><<<(N + 63) / 64, 256, 0, stream>>>(bufA, W, as_, ad_, hbuf, hs, hd, N);
        k_edge_alpha<<<(E + N + tb - 1) / tb, tb, 0, stream>>>(src, dst, eattr, mean_attr, hs, hd, wea + 16, invp, alpha_csr, alpha_self, E, N);
        k_aggregate<64, false><<<nwave_blocks, tb, 0, stream>>>(hbuf, rowstart, deg, src_csr, alpha_csr, alpha_self, b, (float*)d_out, N);
    }
}

// Round 5
// 378.499 us; speedup vs baseline: 2.9894x; 1.0736x over previous
//
#include <hip/hip_runtime.h>
#include <hip/hip_fp16.h>
#include <cstdint>

#define NEG_SLOPE 0.2f

// ---------- preprocessing ----------

__global__ void k_count(const int* __restrict__ dst, int* __restrict__ deg, int E) {
    int e = blockIdx.x * blockDim.x + threadIdx.x;
    if (e < E) atomicAdd(deg + dst[e], 1);
}

__global__ void k_scan_block(const int* __restrict__ in, int* __restrict__ out,
                             int* __restrict__ partials, int n) {
    __shared__ int s[256];
    int i = blockIdx.x * 256 + threadIdx.x;
    int v = (i < n) ? in[i] : 0;
    s[threadIdx.x] = v;
    __syncthreads();
    for (int off = 1; off < 256; off <<= 1) {
        int t = (threadIdx.x >= off) ? s[threadIdx.x - off] : 0;
        __syncthreads();
        s[threadIdx.x] += t;
        __syncthreads();
    }
    if (i < n) out[i] = s[threadIdx.x] - v;   // exclusive
    if (threadIdx.x == 255) partials[blockIdx.x] = s[255];
}

__global__ void k_scan_partials(int* __restrict__ partials, int nb) {
    __shared__ int s[256];
    int v = (threadIdx.x < nb) ? partials[threadIdx.x] : 0;
    s[threadIdx.x] = v;
    __syncthreads();
    for (int off = 1; off < 256; off <<= 1) {
        int t = (threadIdx.x >= off) ? s[threadIdx.x - off] : 0;
        __syncthreads();
        s[threadIdx.x] += t;
        __syncthreads();
    }
    if (threadIdx.x < nb) partials[threadIdx.x] = s[threadIdx.x] - v;  // exclusive
}

__global__ void k_add_offsets(int* __restrict__ rowstart, int* __restrict__ cursor,
                              const int* __restrict__ partials, int n) {
    int i = blockIdx.x * 256 + threadIdx.x;
    if (i >= n) return;
    int r = rowstart[i] + partials[blockIdx.x];
    rowstart[i] = r;
    cursor[i] = r;
}

__global__ void k_fill_csr(const int* __restrict__ src, const int* __restrict__ dst,
                           int* __restrict__ cursor, int* __restrict__ eid,
                           int* __restrict__ src_csr, int* __restrict__ inv, int E) {
    int e = blockIdx.x * blockDim.x + threadIdx.x;
    if (e >= E) return;
    int pos = atomicAdd(cursor + dst[e], 1);
    eid[pos] = e;
    src_csr[pos] = src[e];
    inv[e] = pos;
}

// wave per node: lanes (j0*8+k) sum attr k of edges j0, j0+8, ... then reduce
__global__ void k_mean_csr(const float* __restrict__ ea, const int* __restrict__ rowstart,
                           const int* __restrict__ deg, const int* __restrict__ eid,
                           float* __restrict__ mean_attr, int n) {
    int t = blockIdx.x * blockDim.x + threadIdx.x;
    int wid = t >> 6, lane = t & 63;
    if (wid >= n) return;
    int start = rowstart[wid], d = deg[wid];
    int j0 = lane >> 3, k = lane & 7;
    float s = 0.f;
    for (int j = j0; j < d; j += 8) s += ea[(size_t)eid[start + j] * 8 + k];
    s += __shfl_xor(s, 8);
    s += __shfl_xor(s, 16);
    s += __shfl_xor(s, 32);
    if (lane < 8) {
        int dd = d < 1 ? 1 : d;
        mean_attr[(size_t)wid * 8 + lane] = s / (float)dd;
    }
}

// ---------- fused GEMM + attention dots (fp16 H output), K-tiled LDS ----------
// BM*DOUT = 4096 outputs/block (16 per thread as 4x4). KT=32 K-tile:
// sX[BM][KT] + sW[KT][DOUT] = 20KB (DOUT=128) / 16KB (DOUT=64) -> high occupancy.

template<int DIN, int DOUT>
__global__ __launch_bounds__(256) void k_gemm_dots(
    const float* __restrict__ X, const float* __restrict__ W,
    const float* __restrict__ as_, const float* __restrict__ ad_,
    __half* __restrict__ H, float* __restrict__ hs, float* __restrict__ hd, int n)
{
    constexpr int GROUP = DOUT / 4;     // threads per row-quad (32 or 16)
    constexpr int BM = 4096 / DOUT;     // rows per block (32 or 64)
    constexpr int KT = 32;
    __shared__ float sX[BM * KT];
    __shared__ float sW[KT * DOUT];

    int tid = threadIdx.x;
    int row_base = blockIdx.x * BM;
    int rows_avail = n - row_base; if (rows_avail > BM) rows_avail = BM;

    int r0 = (tid / GROUP) * 4;
    int c0 = (tid % GROUP) * 4;

    float acc[4][4] = {};

    for (int kt = 0; kt < DIN; kt += KT) {
        // X tile: BM*KT/4 float4
        {
            constexpr int XV = BM * KT / 4;
            float4* sXv = (float4*)sX;
#pragma unroll
            for (int i = tid; i < XV; i += 256) {
                int row = i / (KT / 4), cc = i % (KT / 4);
                if (row < rows_avail)
                    sXv[i] = *(const float4*)&X[(size_t)(row_base + row) * DIN + kt + cc * 4];
            }
        }
        // W tile: KT*DOUT/4 float4
        {
            constexpr int WV = KT * DOUT / 4;
            float4* sWv = (float4*)sW;
            const float4* Wv = (const float4*)(W + (size_t)kt * DOUT);
#pragma unroll
            for (int i = tid; i < WV; i += 256) sWv[i] = Wv[i];
        }
        __syncthreads();

#pragma unroll 8
        for (int k = 0; k < KT; k++) {
            float4 w = *(const float4*)&sW[k * DOUT + c0];
            float xv[4];
#pragma unroll
            for (int i = 0; i < 4; i++) xv[i] = sX[(r0 + i) * KT + k];
#pragma unroll
            for (int i = 0; i < 4; i++) {
                acc[i][0] = fmaf(xv[i], w.x, acc[i][0]);
                acc[i][1] = fmaf(xv[i], w.y, acc[i][1]);
                acc[i][2] = fmaf(xv[i], w.z, acc[i][2]);
                acc[i][3] = fmaf(xv[i], w.w, acc[i][3]);
            }
        }
        __syncthreads();
    }

    float4 av = *(const float4*)&as_[c0];
    float4 dv = *(const float4*)&ad_[c0];

#pragma unroll
    for (int i = 0; i < 4; i++) {
        int row = row_base + r0 + i;
        bool ok = row < n;
        if (ok) {
            __half2 p0 = __floats2half2_rn(acc[i][0], acc[i][1]);
            __half2 p1 = __floats2half2_rn(acc[i][2], acc[i][3]);
            __half2* dst2 = (__half2*)&H[(size_t)row * DOUT + c0];
            dst2[0] = p0;
            dst2[1] = p1;
        }
        float ps = acc[i][0] * av.x + acc[i][1] * av.y + acc[i][2] * av.z + acc[i][3] * av.w;
        float pd = acc[i][0] * dv.x + acc[i][1] * dv.y + acc[i][2] * dv.z + acc[i][3] * dv.w;
#pragma unroll
        for (int off = GROUP / 2; off; off >>= 1) {
            ps += __shfl_xor(ps, off);
            pd += __shfl_xor(pd, off);
        }
        if (ok && (tid % GROUP) == 0) { hs[row] = ps; hd[row] = pd; }
    }
}

// ---------- per-layer edge/aggregate kernels ----------

__global__ void k_wea_all(const float* __restrict__ We0, const float* __restrict__ ae0,
                          const float* __restrict__ We1, const float* __restrict__ ae1,
                          const float* __restrict__ We2, const float* __restrict__ ae2,
                          float* __restrict__ wea) {
    int j = threadIdx.x;
    if (j >= 24) return;
    int layer = j >> 3, k = j & 7;
    const float* We = layer == 0 ? We0 : (layer == 1 ? We1 : We2);
    const float* ae = layer == 0 ? ae0 : (layer == 1 ? ae1 : ae2);
    int D = layer == 2 ? 64 : 128;
    float s = 0.f;
    for (int t = 0; t < D; t++) s = fmaf(We[(size_t)k * D + t], ae[t], s);
    wea[j] = s;
}

// alpha written directly in CSR order via inv[]; self-loop alpha to dense array
__global__ void k_edge_alpha(const int* __restrict__ src, const int* __restrict__ dst,
                             const float* __restrict__ ea, const float* __restrict__ mean_attr,
                             const float* __restrict__ hs, const float* __restrict__ hd,
                             const float* __restrict__ wea, const int* __restrict__ inv,
                             float* __restrict__ alpha_csr, float* __restrict__ alpha_self,
                             int E, int n) {
    int e = blockIdx.x * blockDim.x + threadIdx.x;
    if (e >= E + n) return;
    int s, d;
    const float* a;
    if (e < E) { s = src[e]; d = dst[e]; a = ea + (size_t)e * 8; }
    else       { s = e - E;  d = s;      a = mean_attr + (size_t)s * 8; }
    float4 a0 = *(const float4*)a;
    float4 a1 = *(const float4*)(a + 4);
    float4 w0 = *(const float4*)wea;
    float4 w1 = *(const float4*)(wea + 4);
    float al = hs[s] + hd[d];
    al = fmaf(a0.x, w0.x, al); al = fmaf(a0.y, w0.y, al);
    al = fmaf(a0.z, w0.z, al); al = fmaf(a0.w, w0.w, al);
    al = fmaf(a1.x, w1.x, al); al = fmaf(a1.y, w1.y, al);
    al = fmaf(a1.z, w1.z, al); al = fmaf(a1.w, w1.w, al);
    al = al > 0.f ? al : NEG_SLOPE * al;
    if (e < E) alpha_csr[inv[e]] = al;
    else       alpha_self[e - E] = al;
}

// wave per node; per-64-edge chunk: coalesced alpha/src loads, lane-parallel exp,
// wave-reduced denom, then shfl-broadcast gather loop (addresses register-resident).
template<int DOUT, bool RELU>
__global__ void k_aggregate(const __half* __restrict__ H, const int* __restrict__ rowstart,
                            const int* __restrict__ deg, const int* __restrict__ src_csr,
                            const float* __restrict__ alpha_csr,
                            const float* __restrict__ alpha_self, const float* __restrict__ bias,
                            float* __restrict__ out, int n) {
    int t = blockIdx.x * blockDim.x + threadIdx.x;
    int wid = t >> 6, lane = t & 63;
    if (wid >= n) return;
    int start = rowstart[wid], d = deg[wid];
    float aself = alpha_self[wid];

    // pass 1: segment max (coalesced alpha reads)
    float m = aself;
    for (int j = lane; j < d; j += 64) m = fmaxf(m, alpha_csr[start + j]);
#pragma unroll
    for (int off = 32; off; off >>= 1) m = fmaxf(m, __shfl_xor(m, off));

    constexpr int V = DOUT / 64;
    float acc[V];
    float denom;
    {
        float w = expf(aself - m);
        denom = w;
        const __half* h = H + (size_t)wid * DOUT;
        if constexpr (V == 2) {
            float2 f = __half22float2(((const __half2*)h)[lane]);
            acc[0] = w * f.x; acc[1] = w * f.y;
        } else {
            acc[0] = w * __half2float(h[lane]);
        }
    }

    for (int base = 0; base < d; base += 64) {
        int rem = d - base; if (rem > 64) rem = 64;
        float a = -3.0e38f;
        int s = 0;
        if (lane < rem) {
            a = alpha_csr[start + base + lane];
            s = src_csr[start + base + lane];
        }
        float ex = expf(a - m);                 // masked lanes -> 0
        float exs = ex;
#pragma unroll
        for (int off = 32; off; off >>= 1) exs += __shfl_xor(exs, off);
        denom += exs;

#pragma unroll 8
        for (int j = 0; j < rem; j++) {
            float w = __shfl(ex, j);
            int sj = __shfl(s, j);
            const __half* h = H + (size_t)sj * DOUT;
            if constexpr (V == 2) {
                float2 f = __half22float2(((const __half2*)h)[lane]);
                acc[0] = fmaf(w, f.x, acc[0]);
                acc[1] = fmaf(w, f.y, acc[1]);
            } else {
                acc[0] = fmaf(w, __half2float(h[lane]), acc[0]);
            }
        }
    }

    float inv = 1.0f / (denom + 1e-16f);
#pragma unroll
    for (int v = 0; v < V; v++) {
        float o = acc[v] * inv + bias[lane * V + v];
        if (RELU) o = fmaxf(o, 0.f);
        out[(size_t)wid * DOUT + lane * V + v] = o;
    }
}

// ---------- launch ----------

extern "C" void kernel_launch(void* const* d_in, const int* in_sizes, int n_in,
                              void* d_out, int out_size, void* d_ws, size_t ws_size,
                              hipStream_t stream) {
    const float* x     = (const float*)d_in[0];
    const int*   eidx  = (const int*)d_in[1];
    const float* eattr = (const float*)d_in[2];
    const int N = in_sizes[0] / 128;
    const int E = in_sizes[1] / 2;
    const int* src = eidx;
    const int* dst = eidx + E;

    char* ws = (char*)d_ws;
    size_t off = 0;
    auto alloc = [&](size_t bytes) -> void* {
        void* p = ws + off;
        off += (bytes + 255) & ~(size_t)255;
        return p;
    };
    float*  bufA      = (float*)alloc((size_t)N * 128 * sizeof(float));
    __half* hbuf      = (__half*)alloc((size_t)N * 128 * sizeof(__half));
    float*  mean_attr = (float*)alloc((size_t)N * 8 * sizeof(float));
    int*    deg       = (int*)alloc((size_t)N * sizeof(int));
    int*    rowstart  = (int*)alloc((size_t)N * sizeof(int));
    int*    cursor    = (int*)alloc((size_t)N * sizeof(int));
    float*  hs        = (float*)alloc((size_t)N * sizeof(float));
    float*  hd        = (float*)alloc((size_t)N * sizeof(float));
    float*  alpha_csr = (float*)alloc((size_t)E * sizeof(float));
    float*  alpha_self= (float*)alloc((size_t)N * sizeof(float));
    int*    eid       = (int*)alloc((size_t)E * sizeof(int));
    int*    src_csr   = (int*)alloc((size_t)E * sizeof(int));
    int*    invp      = (int*)alloc((size_t)E * sizeof(int));
    float*  wea       = (float*)alloc(64 * sizeof(float));
    int*    partials  = (int*)alloc(256 * sizeof(int));

    const int tb = 256;
    hipMemsetAsync(deg, 0, (size_t)N * sizeof(int), stream);

    k_count<<<(E + tb - 1) / tb, tb, 0, stream>>>(dst, deg, E);
    int nb = (N + 255) / 256;
    k_scan_block<<<nb, 256, 0, stream>>>(deg, rowstart, partials, N);
    k_scan_partials<<<1, 256, 0, stream>>>(partials, nb);
    k_add_offsets<<<nb, 256, 0, stream>>>(rowstart, cursor, partials, N);
    k_fill_csr<<<(E + tb - 1) / tb, tb, 0, stream>>>(src, dst, cursor, eid, src_csr, invp, E);
    int nwave_blocks = (N * 64 + tb - 1) / tb;
    k_mean_csr<<<nwave_blocks, tb, 0, stream>>>(eattr, rowstart, deg, eid, mean_attr, N);
    k_wea_all<<<1, 64, 0, stream>>>((const float*)d_in[6], (const float*)d_in[7],
                                    (const float*)d_in[12], (const float*)d_in[13],
                                    (const float*)d_in[18], (const float*)d_in[19], wea);

    // ---- layer 0 (128->128, relu) ----
    {
        const float* W   = (const float*)d_in[3];
        const float* as_ = (const float*)d_in[4];
        const float* ad_ = (const float*)d_in[5];
        const float* b   = (const float*)d_in[8];
        k_gemm_dots<128, 128><<<(N + 31) / 32, 256, 0, stream>>>(x, W, as_, ad_, hbuf, hs, hd, N);
        k_edge_alpha<<<(E + N + tb - 1) / tb, tb, 0, stream>>>(src, dst, eattr, mean_attr, hs, hd, wea, invp, alpha_csr, alpha_self, E, N);
        k_aggregate<128, true><<<nwave_blocks, tb, 0, stream>>>(hbuf, rowstart, deg, src_csr, alpha_csr, alpha_self, b, bufA, N);
    }
    // ---- layer 1 (128->128, relu) ----
    {
        const float* W   = (const float*)d_in[9];
        const float* as_ = (const float*)d_in[10];
        const float* ad_ = (const float*)d_in[11];
        const float* b   = (const float*)d_in[14];
        k_gemm_dots<128, 128><<<(N + 31) / 32, 256, 0, stream>>>(bufA, W, as_, ad_, hbuf, hs, hd, N);
        k_edge_alpha<<<(E + N + tb - 1) / tb, tb, 0, stream>>>(src, dst, eattr, mean_attr, hs, hd, wea + 8, invp, alpha_csr, alpha_self, E, N);
        k_aggregate<128, true><<<nwave_blocks, tb, 0, stream>>>(hbuf, rowstart, deg, src_csr, alpha_csr, alpha_self, b, bufA, N);
    }
    // ---- layer 2 (128->64, no relu) ----
    {
        const float* W   = (const float*)d_in[15];
        const float* as_ = (const float*)d_in[16];
        const float* ad_ = (const float*)d_in[17];
        const float* b   = (const float*)d_in[20];
        k_gemm_dots<128, 64><<<(N + 63) / 64, 256, 0, stream>>>(bufA, W, as_, ad_, hbuf, hs, hd, N);
        k_edge_alpha<<<(E + N + tb - 1) / tb, tb, 0, stream>>>(src, dst, eattr, mean_attr, hs, hd, wea + 16, invp, alpha_csr, alpha_self, E, N);
        k_aggregate<64, false><<<nwave_blocks, tb, 0, stream>>>(hbuf, rowstart, deg, src_csr, alpha_csr, alpha_self, b, (float*)d_out, N);
    }
}

// Round 6
// 333.384 us; speedup vs baseline: 3.3940x; 1.1353x over previous
//
#include <hip/hip_runtime.h>
#include <hip/hip_fp16.h>
#include <cstdint>

#define NEG_SLOPE 0.2f

// ---------- preprocessing ----------

__global__ void k_count(const int* __restrict__ dst, int* __restrict__ deg, int E) {
    int e = blockIdx.x * blockDim.x + threadIdx.x;
    if (e < E) atomicAdd(deg + dst[e], 1);
}

__global__ void k_scan_block(const int* __restrict__ in, int* __restrict__ out,
                             int* __restrict__ partials, int n) {
    __shared__ int s[256];
    int i = blockIdx.x * 256 + threadIdx.x;
    int v = (i < n) ? in[i] : 0;
    s[threadIdx.x] = v;
    __syncthreads();
    for (int off = 1; off < 256; off <<= 1) {
        int t = (threadIdx.x >= off) ? s[threadIdx.x - off] : 0;
        __syncthreads();
        s[threadIdx.x] += t;
        __syncthreads();
    }
    if (i < n) out[i] = s[threadIdx.x] - v;   // exclusive
    if (threadIdx.x == 255) partials[blockIdx.x] = s[255];
}

__global__ void k_scan_partials(int* __restrict__ partials, int nb) {
    __shared__ int s[256];
    int v = (threadIdx.x < nb) ? partials[threadIdx.x] : 0;
    s[threadIdx.x] = v;
    __syncthreads();
    for (int off = 1; off < 256; off <<= 1) {
        int t = (threadIdx.x >= off) ? s[threadIdx.x - off] : 0;
        __syncthreads();
        s[threadIdx.x] += t;
        __syncthreads();
    }
    if (threadIdx.x < nb) partials[threadIdx.x] = s[threadIdx.x] - v;  // exclusive
}

__global__ void k_add_offsets(int* __restrict__ rowstart, int* __restrict__ cursor,
                              const int* __restrict__ partials, int n) {
    int i = blockIdx.x * 256 + threadIdx.x;
    if (i >= n) return;
    int r = rowstart[i] + partials[blockIdx.x];
    rowstart[i] = r;
    cursor[i] = r;
}

__global__ void k_fill_csr(const int* __restrict__ src, const int* __restrict__ dst,
                           int* __restrict__ cursor, int* __restrict__ eid,
                           int* __restrict__ src_csr, int* __restrict__ inv, int E) {
    int e = blockIdx.x * blockDim.x + threadIdx.x;
    if (e >= E) return;
    int pos = atomicAdd(cursor + dst[e], 1);
    eid[pos] = e;
    src_csr[pos] = src[e];
    inv[e] = pos;
}

// wave per node: lanes (j0*8+k) sum attr k of edges j0, j0+8, ... then reduce
__global__ void k_mean_csr(const float* __restrict__ ea, const int* __restrict__ rowstart,
                           const int* __restrict__ deg, const int* __restrict__ eid,
                           float* __restrict__ mean_attr, int n) {
    int t = blockIdx.x * blockDim.x + threadIdx.x;
    int wid = t >> 6, lane = t & 63;
    if (wid >= n) return;
    int start = rowstart[wid], d = deg[wid];
    int j0 = lane >> 3, k = lane & 7;
    float s = 0.f;
    for (int j = j0; j < d; j += 8) s += ea[(size_t)eid[start + j] * 8 + k];
    s += __shfl_xor(s, 8);
    s += __shfl_xor(s, 16);
    s += __shfl_xor(s, 32);
    if (lane < 8) {
        int dd = d < 1 ? 1 : d;
        mean_attr[(size_t)wid * 8 + lane] = s / (float)dd;
    }
}

__global__ void k_wea_all(const float* __restrict__ We0, const float* __restrict__ ae0,
                          const float* __restrict__ We1, const float* __restrict__ ae1,
                          const float* __restrict__ We2, const float* __restrict__ ae2,
                          float* __restrict__ wea) {
    int j = threadIdx.x;
    if (j >= 24) return;
    int layer = j >> 3, k = j & 7;
    const float* We = layer == 0 ? We0 : (layer == 1 ? We1 : We2);
    const float* ae = layer == 0 ? ae0 : (layer == 1 ? ae1 : ae2);
    int D = layer == 2 ? 64 : 128;
    float s = 0.f;
    for (int t = 0; t < D; t++) s = fmaf(We[(size_t)k * D + t], ae[t], s);
    wea[j] = s;
}

// per-edge attr dots for ALL 3 layers in one pass; scattered into CSR order
__global__ void k_ead(const float* __restrict__ ea, const float* __restrict__ mean_attr,
                      const float* __restrict__ wea, const int* __restrict__ inv,
                      float* __restrict__ e0, float* __restrict__ e1, float* __restrict__ e2,
                      float* __restrict__ s0, float* __restrict__ s1, float* __restrict__ s2,
                      int E, int n) {
    int e = blockIdx.x * blockDim.x + threadIdx.x;
    if (e >= E + n) return;
    const float* a = (e < E) ? ea + (size_t)e * 8 : mean_attr + (size_t)(e - E) * 8;
    float4 a0 = *(const float4*)a;
    float4 a1 = *(const float4*)(a + 4);
    float d0 = 0.f, d1 = 0.f, d2 = 0.f;
    {
        float4 w0 = *(const float4*)&wea[0], w1 = *(const float4*)&wea[4];
        d0 = a0.x*w0.x + a0.y*w0.y + a0.z*w0.z + a0.w*w0.w
           + a1.x*w1.x + a1.y*w1.y + a1.z*w1.z + a1.w*w1.w;
    }
    {
        float4 w0 = *(const float4*)&wea[8], w1 = *(const float4*)&wea[12];
        d1 = a0.x*w0.x + a0.y*w0.y + a0.z*w0.z + a0.w*w0.w
           + a1.x*w1.x + a1.y*w1.y + a1.z*w1.z + a1.w*w1.w;
    }
    {
        float4 w0 = *(const float4*)&wea[16], w1 = *(const float4*)&wea[20];
        d2 = a0.x*w0.x + a0.y*w0.y + a0.z*w0.z + a0.w*w0.w
           + a1.x*w1.x + a1.y*w1.y + a1.z*w1.z + a1.w*w1.w;
    }
    if (e < E) {
        int p = inv[e];
        e0[p] = d0; e1[p] = d1; e2[p] = d2;
    } else {
        int i = e - E;
        s0[i] = d0; s1[i] = d1; s2[i] = d2;
    }
}

// ---------- fused GEMM + attention dots (fp16 H output), K-tiled LDS ----------

template<int DIN, int DOUT>
__global__ __launch_bounds__(256) void k_gemm_dots(
    const float* __restrict__ X, const float* __restrict__ W,
    const float* __restrict__ as_, const float* __restrict__ ad_,
    __half* __restrict__ H, float* __restrict__ hs, float* __restrict__ hd, int n)
{
    constexpr int GROUP = DOUT / 4;     // threads per row-quad (32 or 16)
    constexpr int BM = 4096 / DOUT;     // rows per block (32 or 64)
    constexpr int KT = 32;
    __shared__ float sX[BM * KT];
    __shared__ float sW[KT * DOUT];

    int tid = threadIdx.x;
    int row_base = blockIdx.x * BM;
    int rows_avail = n - row_base; if (rows_avail > BM) rows_avail = BM;

    int r0 = (tid / GROUP) * 4;
    int c0 = (tid % GROUP) * 4;

    float acc[4][4] = {};

    for (int kt = 0; kt < DIN; kt += KT) {
        {
            constexpr int XV = BM * KT / 4;
            float4* sXv = (float4*)sX;
#pragma unroll
            for (int i = tid; i < XV; i += 256) {
                int row = i / (KT / 4), cc = i % (KT / 4);
                if (row < rows_avail)
                    sXv[i] = *(const float4*)&X[(size_t)(row_base + row) * DIN + kt + cc * 4];
            }
        }
        {
            constexpr int WV = KT * DOUT / 4;
            float4* sWv = (float4*)sW;
            const float4* Wv = (const float4*)(W + (size_t)kt * DOUT);
#pragma unroll
            for (int i = tid; i < WV; i += 256) sWv[i] = Wv[i];
        }
        __syncthreads();

#pragma unroll 8
        for (int k = 0; k < KT; k++) {
            float4 w = *(const float4*)&sW[k * DOUT + c0];
            float xv[4];
#pragma unroll
            for (int i = 0; i < 4; i++) xv[i] = sX[(r0 + i) * KT + k];
#pragma unroll
            for (int i = 0; i < 4; i++) {
                acc[i][0] = fmaf(xv[i], w.x, acc[i][0]);
                acc[i][1] = fmaf(xv[i], w.y, acc[i][1]);
                acc[i][2] = fmaf(xv[i], w.z, acc[i][2]);
                acc[i][3] = fmaf(xv[i], w.w, acc[i][3]);
            }
        }
        __syncthreads();
    }

    float4 av = *(const float4*)&as_[c0];
    float4 dv = *(const float4*)&ad_[c0];

#pragma unroll
    for (int i = 0; i < 4; i++) {
        int row = row_base + r0 + i;
        bool ok = row < n;
        if (ok) {
            __half2 p0 = __floats2half2_rn(acc[i][0], acc[i][1]);
            __half2 p1 = __floats2half2_rn(acc[i][2], acc[i][3]);
            __half2* dst2 = (__half2*)&H[(size_t)row * DOUT + c0];
            dst2[0] = p0;
            dst2[1] = p1;
        }
        float ps = acc[i][0] * av.x + acc[i][1] * av.y + acc[i][2] * av.z + acc[i][3] * av.w;
        float pd = acc[i][0] * dv.x + acc[i][1] * dv.y + acc[i][2] * dv.z + acc[i][3] * dv.w;
#pragma unroll
        for (int off = GROUP / 2; off; off >>= 1) {
            ps += __shfl_xor(ps, off);
            pd += __shfl_xor(pd, off);
        }
        if (ok && (tid % GROUP) == 0) { hs[row] = ps; hd[row] = pd; }
    }
}

// ---------- fused alpha + softmax + aggregate ----------
// wave per node; alpha computed inline (hs gather + hd broadcast + precomputed ead).
// gather loop: 2 edges/iter (lane halves), 8B fp16 loads, final shfl_xor(32) combine.

template<int CPL>
__device__ __forceinline__ void accum_row(float* acc, const __half* __restrict__ hrow,
                                          int l, float w) {
    if constexpr (CPL == 4) {
        float2 raw = *(const float2*)(hrow + 4 * l);
        __half2 ha = *(__half2*)&raw.x;
        __half2 hb = *(__half2*)&raw.y;
        float2 fa = __half22float2(ha), fb = __half22float2(hb);
        acc[0] = fmaf(w, fa.x, acc[0]); acc[1] = fmaf(w, fa.y, acc[1]);
        acc[2] = fmaf(w, fb.x, acc[2]); acc[3] = fmaf(w, fb.y, acc[3]);
    } else {
        __half2 ha = *(const __half2*)(hrow + 2 * l);
        float2 fa = __half22float2(ha);
        acc[0] = fmaf(w, fa.x, acc[0]); acc[1] = fmaf(w, fa.y, acc[1]);
    }
}

template<int DOUT, bool RELU>
__global__ void k_aggregate(const __half* __restrict__ H, const int* __restrict__ rowstart,
                            const int* __restrict__ deg, const int* __restrict__ src_csr,
                            const float* __restrict__ ead_csr, const float* __restrict__ ead_self,
                            const float* __restrict__ hs, const float* __restrict__ hd,
                            const float* __restrict__ bias, float* __restrict__ out, int n) {
    int t = blockIdx.x * blockDim.x + threadIdx.x;
    int wid = t >> 6, lane = t & 63;
    if (wid >= n) return;
    int start = rowstart[wid], d = deg[wid];
    int half = lane >> 5, l = lane & 31;
    float hdv = hd[wid];
    float aself = hs[wid] + hdv + ead_self[wid];
    aself = aself > 0.f ? aself : NEG_SLOPE * aself;

    constexpr int CPL = DOUT / 32;
    float acc[CPL] = {};
    float denom;

    if (d <= 64) {
        // single-pass: load once, max+exp+aggregate from registers
        float al = -3.0e38f; int s = 0;
        if (lane < d) {
            int p = start + lane;
            s = src_csr[p];
            float a = hs[s] + hdv + ead_csr[p];
            al = a > 0.f ? a : NEG_SLOPE * a;
        }
        float m = fmaxf(al, aself);
#pragma unroll
        for (int off = 32; off; off >>= 1) m = fmaxf(m, __shfl_xor(m, off));
        float ex = (lane < d) ? expf(al - m) : 0.f;
        float exsum = ex;
#pragma unroll
        for (int off = 32; off; off >>= 1) exsum += __shfl_xor(exsum, off);
        float exself = expf(aself - m);
        denom = exsum + exself;

        if (half == 0) accum_row<CPL>(acc, H + (size_t)wid * DOUT, l, exself);

        int pairs = (d + 1) >> 1;
        for (int jj = 0; jj < pairs; jj++) {
            int j = 2 * jj + half;
            float w = __shfl(ex, j);
            int sj = __shfl(s, j);
            if (j < d) accum_row<CPL>(acc, H + (size_t)sj * DOUT, l, w);
        }
    } else {
        // two-pass chunked (rare)
        float m = aself;
        for (int base = 0; base < d; base += 64) {
            if (base + lane < d) {
                int p = start + base + lane;
                int s = src_csr[p];
                float a = hs[s] + hdv + ead_csr[p];
                a = a > 0.f ? a : NEG_SLOPE * a;
                m = fmaxf(m, a);
            }
        }
#pragma unroll
        for (int off = 32; off; off >>= 1) m = fmaxf(m, __shfl_xor(m, off));
        float exself = expf(aself - m);
        denom = exself;
        if (half == 0) accum_row<CPL>(acc, H + (size_t)wid * DOUT, l, exself);

        for (int base = 0; base < d; base += 64) {
            int rem = d - base; if (rem > 64) rem = 64;
            float ex = 0.f; int s = 0;
            if (lane < rem) {
                int p = start + base + lane;
                s = src_csr[p];
                float a = hs[s] + hdv + ead_csr[p];
                a = a > 0.f ? a : NEG_SLOPE * a;
                ex = expf(a - m);
            }
            float exsum = ex;
#pragma unroll
            for (int off = 32; off; off >>= 1) exsum += __shfl_xor(exsum, off);
            denom += exsum;
            int pairs = (rem + 1) >> 1;
            for (int jj = 0; jj < pairs; jj++) {
                int j = 2 * jj + half;
                float w = __shfl(ex, j);
                int sj = __shfl(s, j);
                if (j < rem) accum_row<CPL>(acc, H + (size_t)sj * DOUT, l, w);
            }
        }
    }

    // combine lane halves (lane l and l+32 hold the same columns)
#pragma unroll
    for (int v = 0; v < CPL; v++) acc[v] += __shfl_xor(acc[v], 32);

    if (half == 0) {
        float inv = 1.0f / (denom + 1e-16f);
        float o[CPL];
#pragma unroll
        for (int v = 0; v < CPL; v++) {
            o[v] = acc[v] * inv + bias[CPL * l + v];
            if (RELU) o[v] = fmaxf(o[v], 0.f);
        }
        if constexpr (CPL == 4) {
            float4 ov = { o[0], o[1], o[2], o[3] };
            *(float4*)&out[(size_t)wid * DOUT + 4 * l] = ov;
        } else {
            float2 ov = { o[0], o[1] };
            *(float2*)&out[(size_t)wid * DOUT + 2 * l] = ov;
        }
    }
}

// ---------- launch ----------

extern "C" void kernel_launch(void* const* d_in, const int* in_sizes, int n_in,
                              void* d_out, int out_size, void* d_ws, size_t ws_size,
                              hipStream_t stream) {
    const float* x     = (const float*)d_in[0];
    const int*   eidx  = (const int*)d_in[1];
    const float* eattr = (const float*)d_in[2];
    const int N = in_sizes[0] / 128;
    const int E = in_sizes[1] / 2;
    const int* src = eidx;
    const int* dst = eidx + E;

    char* ws = (char*)d_ws;
    size_t off = 0;
    auto alloc = [&](size_t bytes) -> void* {
        void* p = ws + off;
        off += (bytes + 255) & ~(size_t)255;
        return p;
    };
    float*  bufA      = (float*)alloc((size_t)N * 128 * sizeof(float));
    __half* hbuf      = (__half*)alloc((size_t)N * 128 * sizeof(__half));
    float*  mean_attr = (float*)alloc((size_t)N * 8 * sizeof(float));
    int*    deg       = (int*)alloc((size_t)N * sizeof(int));
    int*    rowstart  = (int*)alloc((size_t)N * sizeof(int));
    int*    cursor    = (int*)alloc((size_t)N * sizeof(int));
    float*  hs        = (float*)alloc((size_t)N * sizeof(float));
    float*  hd        = (float*)alloc((size_t)N * sizeof(float));
    int*    eid       = (int*)alloc((size_t)E * sizeof(int));
    int*    src_csr   = (int*)alloc((size_t)E * sizeof(int));
    int*    invp      = (int*)alloc((size_t)E * sizeof(int));
    float*  ead0      = (float*)alloc((size_t)E * sizeof(float));
    float*  ead1      = (float*)alloc((size_t)E * sizeof(float));
    float*  ead2      = (float*)alloc((size_t)E * sizeof(float));
    float*  eads0     = (float*)alloc((size_t)N * sizeof(float));
    float*  eads1     = (float*)alloc((size_t)N * sizeof(float));
    float*  eads2     = (float*)alloc((size_t)N * sizeof(float));
    float*  wea       = (float*)alloc(64 * sizeof(float));
    int*    partials  = (int*)alloc(256 * sizeof(int));

    const int tb = 256;
    hipMemsetAsync(deg, 0, (size_t)N * sizeof(int), stream);

    k_count<<<(E + tb - 1) / tb, tb, 0, stream>>>(dst, deg, E);
    int nb = (N + 255) / 256;
    k_scan_block<<<nb, 256, 0, stream>>>(deg, rowstart, partials, N);
    k_scan_partials<<<1, 256, 0, stream>>>(partials, nb);
    k_add_offsets<<<nb, 256, 0, stream>>>(rowstart, cursor, partials, N);
    k_fill_csr<<<(E + tb - 1) / tb, tb, 0, stream>>>(src, dst, cursor, eid, src_csr, invp, E);
    int nwave_blocks = (N * 64 + tb - 1) / tb;
    k_mean_csr<<<nwave_blocks, tb, 0, stream>>>(eattr, rowstart, deg, eid, mean_attr, N);
    k_wea_all<<<1, 64, 0, stream>>>((const float*)d_in[6], (const float*)d_in[7],
                                    (const float*)d_in[12], (const float*)d_in[13],
                                    (const float*)d_in[18], (const float*)d_in[19], wea);
    k_ead<<<(E + N + tb - 1) / tb, tb, 0, stream>>>(eattr, mean_attr, wea, invp,
                                                    ead0, ead1, ead2, eads0, eads1, eads2, E, N);

    // ---- layer 0 (128->128, relu) ----
    {
        const float* W   = (const float*)d_in[3];
        const float* as_ = (const float*)d_in[4];
        const float* ad_ = (const float*)d_in[5];
        const float* b   = (const float*)d_in[8];
        k_gemm_dots<128, 128><<<(N + 31) / 32, 256, 0, stream>>>(x, W, as_, ad_, hbuf, hs, hd, N);
        k_aggregate<128, true><<<nwave_blocks, tb, 0, stream>>>(hbuf, rowstart, deg, src_csr, ead0, eads0, hs, hd, b, bufA, N);
    }
    // ---- layer 1 (128->128, relu) ----
    {
        const float* W   = (const float*)d_in[9];
        const float* as_ = (const float*)d_in[10];
        const float* ad_ = (const float*)d_in[11];
        const float* b   = (const float*)d_in[14];
        k_gemm_dots<128, 128><<<(N + 31) / 32, 256, 0, stream>>>(bufA, W, as_, ad_, hbuf, hs, hd, N);
        k_aggregate<128, true><<<nwave_blocks, tb, 0, stream>>>(hbuf, rowstart, deg, src_csr, ead1, eads1, hs, hd, b, bufA, N);
    }
    // ---- layer 2 (128->64, no relu) ----
    {
        const float* W   = (const float*)d_in[15];
        const float* as_ = (const float*)d_in[16];
        const float* ad_ = (const float*)d_in[17];
        const float* b   = (const float*)d_in[20];
        k_gemm_dots<128, 64><<<(N + 63) / 64, 256, 0, stream>>>(bufA, W, as_, ad_, hbuf, hs, hd, N);
        k_aggregate<64, false><<<nwave_blocks, tb, 0, stream>>>(hbuf, rowstart, deg, src_csr, ead2, eads2, hs, hd, b, (float*)d_out, N);
    }
}

// Round 7
// 293.475 us; speedup vs baseline: 3.8555x; 1.1360x over previous
//
#include <hip/hip_runtime.h>
#include <hip/hip_fp16.h>
#include <cstdint>

#define NEG_SLOPE 0.2f

// ---------- preprocessing ----------

__global__ void k_count(const int* __restrict__ dst, int* __restrict__ deg, int E) {
    int e = blockIdx.x * blockDim.x + threadIdx.x;
    if (e < E) atomicAdd(deg + dst[e], 1);
}

__global__ void k_scan_block(const int* __restrict__ in, int* __restrict__ out,
                             int* __restrict__ partials, int n) {
    __shared__ int s[256];
    int i = blockIdx.x * 256 + threadIdx.x;
    int v = (i < n) ? in[i] : 0;
    s[threadIdx.x] = v;
    __syncthreads();
    for (int off = 1; off < 256; off <<= 1) {
        int t = (threadIdx.x >= off) ? s[threadIdx.x - off] : 0;
        __syncthreads();
        s[threadIdx.x] += t;
        __syncthreads();
    }
    if (i < n) out[i] = s[threadIdx.x] - v;   // exclusive
    if (threadIdx.x == 255) partials[blockIdx.x] = s[255];
}

__global__ void k_scan_partials(int* __restrict__ partials, int nb) {
    __shared__ int s[256];
    int v = (threadIdx.x < nb) ? partials[threadIdx.x] : 0;
    s[threadIdx.x] = v;
    __syncthreads();
    for (int off = 1; off < 256; off <<= 1) {
        int t = (threadIdx.x >= off) ? s[threadIdx.x - off] : 0;
        __syncthreads();
        s[threadIdx.x] += t;
        __syncthreads();
    }
    if (threadIdx.x < nb) partials[threadIdx.x] = s[threadIdx.x] - v;  // exclusive
}

__global__ void k_add_offsets(int* __restrict__ rowstart, int* __restrict__ cursor,
                              const int* __restrict__ partials, int n) {
    int i = blockIdx.x * 256 + threadIdx.x;
    if (i >= n) return;
    int r = rowstart[i] + partials[blockIdx.x];
    rowstart[i] = r;
    cursor[i] = r;
}

__global__ void k_wea_all(const float* __restrict__ We0, const float* __restrict__ ae0,
                          const float* __restrict__ We1, const float* __restrict__ ae1,
                          const float* __restrict__ We2, const float* __restrict__ ae2,
                          float* __restrict__ wea) {
    int j = threadIdx.x;
    if (j >= 24) return;
    int layer = j >> 3, k = j & 7;
    const float* We = layer == 0 ? We0 : (layer == 1 ? We1 : We2);
    const float* ae = layer == 0 ? ae0 : (layer == 1 ? ae1 : ae2);
    int D = layer == 2 ? 64 : 128;
    float s = 0.f;
    for (int t = 0; t < D; t++) s = fmaf(We[(size_t)k * D + t], ae[t], s);
    wea[j] = s;
}

// CSR fill + per-edge attr dots for all 3 layers, packed {src, ead} per layer.
// Self-loop mean term is recovered in the aggregate as mean(ead) over the row.
__global__ void k_fill_ext(const int* __restrict__ src, const int* __restrict__ dst,
                           const float* __restrict__ ea, const float* __restrict__ wea,
                           int* __restrict__ cursor,
                           int2* __restrict__ ed0, int2* __restrict__ ed1,
                           int2* __restrict__ ed2, int E) {
    int e = blockIdx.x * blockDim.x + threadIdx.x;
    if (e >= E) return;
    int s = src[e];
    int pos = atomicAdd(cursor + dst[e], 1);
    float4 a0 = *(const float4*)&ea[(size_t)e * 8];
    float4 a1 = *(const float4*)&ea[(size_t)e * 8 + 4];
    float4 w00 = *(const float4*)&wea[0],  w01 = *(const float4*)&wea[4];
    float4 w10 = *(const float4*)&wea[8],  w11 = *(const float4*)&wea[12];
    float4 w20 = *(const float4*)&wea[16], w21 = *(const float4*)&wea[20];
    float d0 = a0.x*w00.x + a0.y*w00.y + a0.z*w00.z + a0.w*w00.w
             + a1.x*w01.x + a1.y*w01.y + a1.z*w01.z + a1.w*w01.w;
    float d1 = a0.x*w10.x + a0.y*w10.y + a0.z*w10.z + a0.w*w10.w
             + a1.x*w11.x + a1.y*w11.y + a1.z*w11.z + a1.w*w11.w;
    float d2 = a0.x*w20.x + a0.y*w20.y + a0.z*w20.z + a0.w*w20.w
             + a1.x*w21.x + a1.y*w21.y + a1.z*w21.z + a1.w*w21.w;
    ed0[pos] = make_int2(s, __float_as_int(d0));
    ed1[pos] = make_int2(s, __float_as_int(d1));
    ed2[pos] = make_int2(s, __float_as_int(d2));
}

// ---------- fused GEMM + attention dots (fp16 H output), K-tiled LDS ----------

template<int DIN, int DOUT>
__global__ __launch_bounds__(256) void k_gemm_dots(
    const float* __restrict__ X, const float* __restrict__ W,
    const float* __restrict__ as_, const float* __restrict__ ad_,
    __half* __restrict__ H, float* __restrict__ hs, float* __restrict__ hd, int n)
{
    constexpr int GROUP = DOUT / 4;     // threads per row-quad (32 or 16)
    constexpr int BM = 4096 / DOUT;     // rows per block (32 or 64)
    constexpr int KT = 32;
    __shared__ float sX[BM * KT];
    __shared__ float sW[KT * DOUT];

    int tid = threadIdx.x;
    int row_base = blockIdx.x * BM;
    int rows_avail = n - row_base; if (rows_avail > BM) rows_avail = BM;

    int r0 = (tid / GROUP) * 4;
    int c0 = (tid % GROUP) * 4;

    float acc[4][4] = {};

    for (int kt = 0; kt < DIN; kt += KT) {
        {
            constexpr int XV = BM * KT / 4;
            float4* sXv = (float4*)sX;
#pragma unroll
            for (int i = tid; i < XV; i += 256) {
                int row = i / (KT / 4), cc = i % (KT / 4);
                if (row < rows_avail)
                    sXv[i] = *(const float4*)&X[(size_t)(row_base + row) * DIN + kt + cc * 4];
            }
        }
        {
            constexpr int WV = KT * DOUT / 4;
            float4* sWv = (float4*)sW;
            const float4* Wv = (const float4*)(W + (size_t)kt * DOUT);
#pragma unroll
            for (int i = tid; i < WV; i += 256) sWv[i] = Wv[i];
        }
        __syncthreads();

#pragma unroll 8
        for (int k = 0; k < KT; k++) {
            float4 w = *(const float4*)&sW[k * DOUT + c0];
            float xv[4];
#pragma unroll
            for (int i = 0; i < 4; i++) xv[i] = sX[(r0 + i) * KT + k];
#pragma unroll
            for (int i = 0; i < 4; i++) {
                acc[i][0] = fmaf(xv[i], w.x, acc[i][0]);
                acc[i][1] = fmaf(xv[i], w.y, acc[i][1]);
                acc[i][2] = fmaf(xv[i], w.z, acc[i][2]);
                acc[i][3] = fmaf(xv[i], w.w, acc[i][3]);
            }
        }
        __syncthreads();
    }

    float4 av = *(const float4*)&as_[c0];
    float4 dv = *(const float4*)&ad_[c0];

#pragma unroll
    for (int i = 0; i < 4; i++) {
        int row = row_base + r0 + i;
        bool ok = row < n;
        if (ok) {
            __half2 p0 = __floats2half2_rn(acc[i][0], acc[i][1]);
            __half2 p1 = __floats2half2_rn(acc[i][2], acc[i][3]);
            __half2* dst2 = (__half2*)&H[(size_t)row * DOUT + c0];
            dst2[0] = p0;
            dst2[1] = p1;
        }
        float ps = acc[i][0] * av.x + acc[i][1] * av.y + acc[i][2] * av.z + acc[i][3] * av.w;
        float pd = acc[i][0] * dv.x + acc[i][1] * dv.y + acc[i][2] * dv.z + acc[i][3] * dv.w;
#pragma unroll
        for (int off = GROUP / 2; off; off >>= 1) {
            ps += __shfl_xor(ps, off);
            pd += __shfl_xor(pd, off);
        }
        if (ok && (tid % GROUP) == 0) { hs[row] = ps; hd[row] = pd; }
    }
}

// ---------- fused alpha + softmax + aggregate ----------

template<int CPL>
__device__ __forceinline__ void accum_row(float* acc, const __half* __restrict__ hrow,
                                          int l, float w) {
    if constexpr (CPL == 4) {
        float2 raw = *(const float2*)(hrow + 4 * l);
        __half2 ha = *(__half2*)&raw.x;
        __half2 hb = *(__half2*)&raw.y;
        float2 fa = __half22float2(ha), fb = __half22float2(hb);
        acc[0] = fmaf(w, fa.x, acc[0]); acc[1] = fmaf(w, fa.y, acc[1]);
        acc[2] = fmaf(w, fb.x, acc[2]); acc[3] = fmaf(w, fb.y, acc[3]);
    } else {
        __half2 ha = *(const __half2*)(hrow + 2 * l);
        float2 fa = __half22float2(ha);
        acc[0] = fmaf(w, fa.x, acc[0]); acc[1] = fmaf(w, fa.y, acc[1]);
    }
}

template<int DOUT, bool RELU>
__global__ void k_aggregate(const __half* __restrict__ H, const int* __restrict__ rowstart,
                            const int* __restrict__ deg, const int2* __restrict__ edata,
                            const float* __restrict__ hs, const float* __restrict__ hd,
                            const float* __restrict__ bias, float* __restrict__ out, int n) {
    int t = blockIdx.x * blockDim.x + threadIdx.x;
    int wid = t >> 6, lane = t & 63;
    if (wid >= n) return;
    int start = rowstart[wid], d = deg[wid];
    int half = lane >> 5, l = lane & 31;
    float hdv = hd[wid];
    float hsw = hs[wid];

    constexpr int CPL = DOUT / 32;
    float acc[CPL] = {};
    float denom;

    if (d <= 64) {
        // single-pass: one packed load per edge, everything from registers
        float al = -3.0e38f; int s = 0; float eadv = 0.f;
        if (lane < d) {
            int2 pv = edata[start + lane];
            s = pv.x; eadv = __int_as_float(pv.y);
            float a = hs[s] + hdv + eadv;
            al = a > 0.f ? a : NEG_SLOPE * a;
        }
        // self-loop attr term = mean(ead) over the row
        float esum = (lane < d) ? eadv : 0.f;
#pragma unroll
        for (int off = 32; off; off >>= 1) esum += __shfl_xor(esum, off);
        int dd = d < 1 ? 1 : d;
        float aself = hsw + hdv + esum / (float)dd;
        aself = aself > 0.f ? aself : NEG_SLOPE * aself;

        float m = fmaxf(al, aself);
#pragma unroll
        for (int off = 32; off; off >>= 1) m = fmaxf(m, __shfl_xor(m, off));
        float ex = (lane < d) ? expf(al - m) : 0.f;
        float exsum = ex;
#pragma unroll
        for (int off = 32; off; off >>= 1) exsum += __shfl_xor(exsum, off);
        float exself = expf(aself - m);
        denom = exsum + exself;

        if (half == 0) accum_row<CPL>(acc, H + (size_t)wid * DOUT, l, exself);

        int pairs = (d + 1) >> 1;
        for (int jj = 0; jj < pairs; jj++) {
            int j = 2 * jj + half;
            float w = __shfl(ex, j);
            int sj = __shfl(s, j);
            if (j < d) accum_row<CPL>(acc, H + (size_t)sj * DOUT, l, w);
        }
    } else {
        // two-pass chunked (rare)
        float m_e = -3.0e38f;
        float esum = 0.f;
        for (int base = 0; base < d; base += 64) {
            if (base + lane < d) {
                int2 pv = edata[start + base + lane];
                float ev = __int_as_float(pv.y);
                esum += ev;
                float a = hs[pv.x] + hdv + ev;
                a = a > 0.f ? a : NEG_SLOPE * a;
                m_e = fmaxf(m_e, a);
            }
        }
#pragma unroll
        for (int off = 32; off; off >>= 1) {
            m_e = fmaxf(m_e, __shfl_xor(m_e, off));
            esum += __shfl_xor(esum, off);
        }
        float aself = hsw + hdv + esum / (float)d;
        aself = aself > 0.f ? aself : NEG_SLOPE * aself;
        float m = fmaxf(m_e, aself);

        float exself = expf(aself - m);
        denom = exself;
        if (half == 0) accum_row<CPL>(acc, H + (size_t)wid * DOUT, l, exself);

        for (int base = 0; base < d; base += 64) {
            int rem = d - base; if (rem > 64) rem = 64;
            float ex = 0.f; int s = 0;
            if (lane < rem) {
                int2 pv = edata[start + base + lane];
                s = pv.x;
                float a = hs[s] + hdv + __int_as_float(pv.y);
                a = a > 0.f ? a : NEG_SLOPE * a;
                ex = expf(a - m);
            }
            float exsum = ex;
#pragma unroll
            for (int off = 32; off; off >>= 1) exsum += __shfl_xor(exsum, off);
            denom += exsum;
            int pairs = (rem + 1) >> 1;
            for (int jj = 0; jj < pairs; jj++) {
                int j = 2 * jj + half;
                float w = __shfl(ex, j);
                int sj = __shfl(s, j);
                if (j < rem) accum_row<CPL>(acc, H + (size_t)sj * DOUT, l, w);
            }
        }
    }

    // combine lane halves (lane l and l+32 hold the same columns)
#pragma unroll
    for (int v = 0; v < CPL; v++) acc[v] += __shfl_xor(acc[v], 32);

    if (half == 0) {
        float inv = 1.0f / (denom + 1e-16f);
        float o[CPL];
#pragma unroll
        for (int v = 0; v < CPL; v++) {
            o[v] = acc[v] * inv + bias[CPL * l + v];
            if (RELU) o[v] = fmaxf(o[v], 0.f);
        }
        if constexpr (CPL == 4) {
            float4 ov = { o[0], o[1], o[2], o[3] };
            *(float4*)&out[(size_t)wid * DOUT + 4 * l] = ov;
        } else {
            float2 ov = { o[0], o[1] };
            *(float2*)&out[(size_t)wid * DOUT + 2 * l] = ov;
        }
    }
}

// ---------- launch ----------

extern "C" void kernel_launch(void* const* d_in, const int* in_sizes, int n_in,
                              void* d_out, int out_size, void* d_ws, size_t ws_size,
                              hipStream_t stream) {
    const float* x     = (const float*)d_in[0];
    const int*   eidx  = (const int*)d_in[1];
    const float* eattr = (const float*)d_in[2];
    const int N = in_sizes[0] / 128;
    const int E = in_sizes[1] / 2;
    const int* src = eidx;
    const int* dst = eidx + E;

    char* ws = (char*)d_ws;
    size_t off = 0;
    auto alloc = [&](size_t bytes) -> void* {
        void* p = ws + off;
        off += (bytes + 255) & ~(size_t)255;
        return p;
    };
    float*  bufA     = (float*)alloc((size_t)N * 128 * sizeof(float));
    __half* hbuf     = (__half*)alloc((size_t)N * 128 * sizeof(__half));
    int*    deg      = (int*)alloc((size_t)N * sizeof(int));
    int*    rowstart = (int*)alloc((size_t)N * sizeof(int));
    int*    cursor   = (int*)alloc((size_t)N * sizeof(int));
    float*  hs       = (float*)alloc((size_t)N * sizeof(float));
    float*  hd       = (float*)alloc((size_t)N * sizeof(float));
    int2*   ed0      = (int2*)alloc((size_t)E * sizeof(int2));
    int2*   ed1      = (int2*)alloc((size_t)E * sizeof(int2));
    int2*   ed2      = (int2*)alloc((size_t)E * sizeof(int2));
    float*  wea      = (float*)alloc(64 * sizeof(float));
    int*    partials = (int*)alloc(256 * sizeof(int));

    const int tb = 256;
    hipMemsetAsync(deg, 0, (size_t)N * sizeof(int), stream);

    k_count<<<(E + tb - 1) / tb, tb, 0, stream>>>(dst, deg, E);
    int nb = (N + 255) / 256;
    k_scan_block<<<nb, 256, 0, stream>>>(deg, rowstart, partials, N);
    k_scan_partials<<<1, 256, 0, stream>>>(partials, nb);
    k_add_offsets<<<nb, 256, 0, stream>>>(rowstart, cursor, partials, N);
    k_wea_all<<<1, 64, 0, stream>>>((const float*)d_in[6], (const float*)d_in[7],
                                    (const float*)d_in[12], (const float*)d_in[13],
                                    (const float*)d_in[18], (const float*)d_in[19], wea);
    k_fill_ext<<<(E + tb - 1) / tb, tb, 0, stream>>>(src, dst, eattr, wea, cursor,
                                                     ed0, ed1, ed2, E);

    int nwave_blocks = (N * 64 + tb - 1) / tb;

    // ---- layer 0 (128->128, relu) ----
    {
        const float* W   = (const float*)d_in[3];
        const float* as_ = (const float*)d_in[4];
        const float* ad_ = (const float*)d_in[5];
        const float* b   = (const float*)d_in[8];
        k_gemm_dots<128, 128><<<(N + 31) / 32, 256, 0, stream>>>(x, W, as_, ad_, hbuf, hs, hd, N);
        k_aggregate<128, true><<<nwave_blocks, tb, 0, stream>>>(hbuf, rowstart, deg, ed0, hs, hd, b, bufA, N);
    }
    // ---- layer 1 (128->128, relu) ----
    {
        const float* W   = (const float*)d_in[9];
        const float* as_ = (const float*)d_in[10];
        const float* ad_ = (const float*)d_in[11];
        const float* b   = (const float*)d_in[14];
        k_gemm_dots<128, 128><<<(N + 31) / 32, 256, 0, stream>>>(bufA, W, as_, ad_, hbuf, hs, hd, N);
        k_aggregate<128, true><<<nwave_blocks, tb, 0, stream>>>(hbuf, rowstart, deg, ed1, hs, hd, b, bufA, N);
    }
    // ---- layer 2 (128->64, no relu) ----
    {
        const float* W   = (const float*)d_in[15];
        const float* as_ = (const float*)d_in[16];
        const float* ad_ = (const float*)d_in[17];
        const float* b   = (const float*)d_in[20];
        k_gemm_dots<128, 64><<<(N + 63) / 64, 256, 0, stream>>>(bufA, W, as_, ad_, hbuf, hs, hd, N);
        k_aggregate<64, false><<<nwave_blocks, tb, 0, stream>>>(hbuf, rowstart, deg, ed2, hs, hd, b, (float*)d_out, N);
    }
}

// Round 8
// 274.360 us; speedup vs baseline: 4.1241x; 1.0697x over previous
//
#include <hip/hip_runtime.h>
#include <hip/hip_fp16.h>
#include <cstdint>

#define NEG_SLOPE 0.2f

// ---------- preprocessing ----------

__global__ void k_count(const int* __restrict__ dst, int* __restrict__ deg, int E) {
    int e = blockIdx.x * blockDim.x + threadIdx.x;
    if (e < E) atomicAdd(deg + dst[e], 1);
}

__global__ void k_scan_block(const int* __restrict__ in, int* __restrict__ out,
                             int* __restrict__ partials, int n) {
    __shared__ int s[256];
    int i = blockIdx.x * 256 + threadIdx.x;
    int v = (i < n) ? in[i] : 0;
    s[threadIdx.x] = v;
    __syncthreads();
    for (int off = 1; off < 256; off <<= 1) {
        int t = (threadIdx.x >= off) ? s[threadIdx.x - off] : 0;
        __syncthreads();
        s[threadIdx.x] += t;
        __syncthreads();
    }
    if (i < n) out[i] = s[threadIdx.x] - v;   // exclusive
    if (threadIdx.x == 255) partials[blockIdx.x] = s[255];
}

__global__ void k_scan_partials(int* __restrict__ partials, int nb) {
    __shared__ int s[256];
    int v = (threadIdx.x < nb) ? partials[threadIdx.x] : 0;
    s[threadIdx.x] = v;
    __syncthreads();
    for (int off = 1; off < 256; off <<= 1) {
        int t = (threadIdx.x >= off) ? s[threadIdx.x - off] : 0;
        __syncthreads();
        s[threadIdx.x] += t;
        __syncthreads();
    }
    if (threadIdx.x < nb) partials[threadIdx.x] = s[threadIdx.x] - v;  // exclusive
}

__global__ void k_add_offsets(int* __restrict__ rowstart, int* __restrict__ cursor,
                              const int* __restrict__ partials, int n) {
    int i = blockIdx.x * 256 + threadIdx.x;
    if (i >= n) return;
    int r = rowstart[i] + partials[blockIdx.x];
    rowstart[i] = r;
    cursor[i] = r;
}

__global__ void k_wea_all(const float* __restrict__ We0, const float* __restrict__ ae0,
                          const float* __restrict__ We1, const float* __restrict__ ae1,
                          const float* __restrict__ We2, const float* __restrict__ ae2,
                          float* __restrict__ wea) {
    int j = threadIdx.x;
    if (j >= 24) return;
    int layer = j >> 3, k = j & 7;
    const float* We = layer == 0 ? We0 : (layer == 1 ? We1 : We2);
    const float* ae = layer == 0 ? ae0 : (layer == 1 ? ae1 : ae2);
    int D = layer == 2 ? 64 : 128;
    float s = 0.f;
    for (int t = 0; t < D; t++) s = fmaf(We[(size_t)k * D + t], ae[t], s);
    wea[j] = s;
}

// CSR fill + per-edge attr dots for all 3 layers, ONE packed int4 {src,d0,d1,d2}.
// Self-loop mean term is recovered in the aggregate as mean(ead) over the row.
__global__ void k_fill_ext(const int* __restrict__ src, const int* __restrict__ dst,
                           const float* __restrict__ ea, const float* __restrict__ wea,
                           int* __restrict__ cursor, int4* __restrict__ ed, int E) {
    int e = blockIdx.x * blockDim.x + threadIdx.x;
    if (e >= E) return;
    int s = src[e];
    int pos = atomicAdd(cursor + dst[e], 1);
    float4 a0 = *(const float4*)&ea[(size_t)e * 8];
    float4 a1 = *(const float4*)&ea[(size_t)e * 8 + 4];
    float4 w00 = *(const float4*)&wea[0],  w01 = *(const float4*)&wea[4];
    float4 w10 = *(const float4*)&wea[8],  w11 = *(const float4*)&wea[12];
    float4 w20 = *(const float4*)&wea[16], w21 = *(const float4*)&wea[20];
    float d0 = a0.x*w00.x + a0.y*w00.y + a0.z*w00.z + a0.w*w00.w
             + a1.x*w01.x + a1.y*w01.y + a1.z*w01.z + a1.w*w01.w;
    float d1 = a0.x*w10.x + a0.y*w10.y + a0.z*w10.z + a0.w*w10.w
             + a1.x*w11.x + a1.y*w11.y + a1.z*w11.z + a1.w*w11.w;
    float d2 = a0.x*w20.x + a0.y*w20.y + a0.z*w20.z + a0.w*w20.w
             + a1.x*w21.x + a1.y*w21.y + a1.z*w21.z + a1.w*w21.w;
    ed[pos] = make_int4(s, __float_as_int(d0), __float_as_int(d1), __float_as_int(d2));
}

// ---------- fused GEMM + attention dots (fp16 H output), K-tiled LDS ----------

template<int DIN, int DOUT>
__global__ __launch_bounds__(256) void k_gemm_dots(
    const float* __restrict__ X, const float* __restrict__ W,
    const float* __restrict__ as_, const float* __restrict__ ad_,
    __half* __restrict__ H, float* __restrict__ hs, float* __restrict__ hd, int n)
{
    constexpr int GROUP = DOUT / 4;     // threads per row-quad (32 or 16)
    constexpr int BM = 4096 / DOUT;     // rows per block (32 or 64)
    constexpr int KT = 32;
    __shared__ float sX[BM * KT];
    __shared__ float sW[KT * DOUT];

    int tid = threadIdx.x;
    int row_base = blockIdx.x * BM;
    int rows_avail = n - row_base; if (rows_avail > BM) rows_avail = BM;

    int r0 = (tid / GROUP) * 4;
    int c0 = (tid % GROUP) * 4;

    float acc[4][4] = {};

    for (int kt = 0; kt < DIN; kt += KT) {
        {
            constexpr int XV = BM * KT / 4;
            float4* sXv = (float4*)sX;
#pragma unroll
            for (int i = tid; i < XV; i += 256) {
                int row = i / (KT / 4), cc = i % (KT / 4);
                if (row < rows_avail)
                    sXv[i] = *(const float4*)&X[(size_t)(row_base + row) * DIN + kt + cc * 4];
            }
        }
        {
            constexpr int WV = KT * DOUT / 4;
            float4* sWv = (float4*)sW;
            const float4* Wv = (const float4*)(W + (size_t)kt * DOUT);
#pragma unroll
            for (int i = tid; i < WV; i += 256) sWv[i] = Wv[i];
        }
        __syncthreads();

#pragma unroll 8
        for (int k = 0; k < KT; k++) {
            float4 w = *(const float4*)&sW[k * DOUT + c0];
            float xv[4];
#pragma unroll
            for (int i = 0; i < 4; i++) xv[i] = sX[(r0 + i) * KT + k];
#pragma unroll
            for (int i = 0; i < 4; i++) {
                acc[i][0] = fmaf(xv[i], w.x, acc[i][0]);
                acc[i][1] = fmaf(xv[i], w.y, acc[i][1]);
                acc[i][2] = fmaf(xv[i], w.z, acc[i][2]);
                acc[i][3] = fmaf(xv[i], w.w, acc[i][3]);
            }
        }
        __syncthreads();
    }

    float4 av = *(const float4*)&as_[c0];
    float4 dv = *(const float4*)&ad_[c0];

#pragma unroll
    for (int i = 0; i < 4; i++) {
        int row = row_base + r0 + i;
        bool ok = row < n;
        if (ok) {
            __half2 p0 = __floats2half2_rn(acc[i][0], acc[i][1]);
            __half2 p1 = __floats2half2_rn(acc[i][2], acc[i][3]);
            __half2* dst2 = (__half2*)&H[(size_t)row * DOUT + c0];
            dst2[0] = p0;
            dst2[1] = p1;
        }
        float ps = acc[i][0] * av.x + acc[i][1] * av.y + acc[i][2] * av.z + acc[i][3] * av.w;
        float pd = acc[i][0] * dv.x + acc[i][1] * dv.y + acc[i][2] * dv.z + acc[i][3] * dv.w;
#pragma unroll
        for (int off = GROUP / 2; off; off >>= 1) {
            ps += __shfl_xor(ps, off);
            pd += __shfl_xor(pd, off);
        }
        if (ok && (tid % GROUP) == 0) { hs[row] = ps; hd[row] = pd; }
    }
}

// ---------- fused alpha + softmax + aggregate ----------
// wave = four 16-lane groups; each group handles every 4th edge (4 gathers in flight).

template<int CPL>
__device__ __forceinline__ void accum_row16(float* acc, const __half* __restrict__ hrow,
                                            int l, float w) {
    if constexpr (CPL == 8) {
        float4 raw = *(const float4*)(hrow + 8 * l);
        __half2* h = (__half2*)&raw;
#pragma unroll
        for (int i = 0; i < 4; i++) {
            float2 f = __half22float2(h[i]);
            acc[2 * i]     = fmaf(w, f.x, acc[2 * i]);
            acc[2 * i + 1] = fmaf(w, f.y, acc[2 * i + 1]);
        }
    } else {
        float2 raw = *(const float2*)(hrow + 4 * l);
        __half2* h = (__half2*)&raw;
#pragma unroll
        for (int i = 0; i < 2; i++) {
            float2 f = __half22float2(h[i]);
            acc[2 * i]     = fmaf(w, f.x, acc[2 * i]);
            acc[2 * i + 1] = fmaf(w, f.y, acc[2 * i + 1]);
        }
    }
}

template<int DOUT, bool RELU, int LCOMP>
__global__ void k_aggregate(const __half* __restrict__ H, const int* __restrict__ rowstart,
                            const int* __restrict__ deg, const int4* __restrict__ edata,
                            const float* __restrict__ hs, const float* __restrict__ hd,
                            const float* __restrict__ bias, float* __restrict__ out, int n) {
    int t = blockIdx.x * blockDim.x + threadIdx.x;
    int wid = t >> 6, lane = t & 63;
    if (wid >= n) return;
    int start = rowstart[wid], d = deg[wid];
    int quarter = lane >> 4, l = lane & 15;
    float hdv = hd[wid];
    float hsw = hs[wid];

    constexpr int CPL = DOUT / 16;
    float acc[CPL] = {};
    float denom;

    if (d <= 64) {
        // single-pass: one packed load per edge, everything from registers
        float al = -3.0e38f; int s = 0; float eadv = 0.f;
        if (lane < d) {
            int4 pv = edata[start + lane];
            s = pv.x;
            eadv = __int_as_float(LCOMP == 1 ? pv.y : LCOMP == 2 ? pv.z : pv.w);
            float a = hs[s] + hdv + eadv;
            al = a > 0.f ? a : NEG_SLOPE * a;
        }
        // self-loop attr term = mean(ead) over the row
        float esum = (lane < d) ? eadv : 0.f;
#pragma unroll
        for (int off = 32; off; off >>= 1) esum += __shfl_xor(esum, off);
        int dd = d < 1 ? 1 : d;
        float aself = hsw + hdv + esum / (float)dd;
        aself = aself > 0.f ? aself : NEG_SLOPE * aself;

        float m = fmaxf(al, aself);
#pragma unroll
        for (int off = 32; off; off >>= 1) m = fmaxf(m, __shfl_xor(m, off));
        float ex = (lane < d) ? expf(al - m) : 0.f;
        float exsum = ex;
#pragma unroll
        for (int off = 32; off; off >>= 1) exsum += __shfl_xor(exsum, off);
        float exself = expf(aself - m);
        denom = exsum + exself;

        if (quarter == 0) accum_row16<CPL>(acc, H + (size_t)wid * DOUT, l, exself);

        int quads = (d + 3) >> 2;
        for (int jj = 0; jj < quads; jj++) {
            int j = 4 * jj + quarter;
            float w = __shfl(ex, j);
            int sj = __shfl(s, j);
            if (j < d) accum_row16<CPL>(acc, H + (size_t)sj * DOUT, l, w);
        }
    } else {
        // two-pass chunked (rare)
        float m_e = -3.0e38f;
        float esum = 0.f;
        for (int base = 0; base < d; base += 64) {
            if (base + lane < d) {
                int4 pv = edata[start + base + lane];
                float ev = __int_as_float(LCOMP == 1 ? pv.y : LCOMP == 2 ? pv.z : pv.w);
                esum += ev;
                float a = hs[pv.x] + hdv + ev;
                a = a > 0.f ? a : NEG_SLOPE * a;
                m_e = fmaxf(m_e, a);
            }
        }
#pragma unroll
        for (int off = 32; off; off >>= 1) {
            m_e = fmaxf(m_e, __shfl_xor(m_e, off));
            esum += __shfl_xor(esum, off);
        }
        float aself = hsw + hdv + esum / (float)d;
        aself = aself > 0.f ? aself : NEG_SLOPE * aself;
        float m = fmaxf(m_e, aself);

        float exself = expf(aself - m);
        denom = exself;
        if (quarter == 0) accum_row16<CPL>(acc, H + (size_t)wid * DOUT, l, exself);

        for (int base = 0; base < d; base += 64) {
            int rem = d - base; if (rem > 64) rem = 64;
            float ex = 0.f; int s = 0;
            if (lane < rem) {
                int4 pv = edata[start + base + lane];
                s = pv.x;
                float a = hs[s] + hdv + __int_as_float(LCOMP == 1 ? pv.y : LCOMP == 2 ? pv.z : pv.w);
                a = a > 0.f ? a : NEG_SLOPE * a;
                ex = expf(a - m);
            }
            float exsum = ex;
#pragma unroll
            for (int off = 32; off; off >>= 1) exsum += __shfl_xor(exsum, off);
            denom += exsum;
            int quads = (rem + 3) >> 2;
            for (int jj = 0; jj < quads; jj++) {
                int j = 4 * jj + quarter;
                float w = __shfl(ex, j);
                int sj = __shfl(s, j);
                if (j < rem) accum_row16<CPL>(acc, H + (size_t)sj * DOUT, l, w);
            }
        }
    }

    // combine the four 16-lane groups (same columns in each)
#pragma unroll
    for (int v = 0; v < CPL; v++) {
        acc[v] += __shfl_xor(acc[v], 16);
        acc[v] += __shfl_xor(acc[v], 32);
    }

    if (lane < 16) {
        float inv = 1.0f / (denom + 1e-16f);
        float o[CPL];
#pragma unroll
        for (int v = 0; v < CPL; v++) {
            o[v] = acc[v] * inv + bias[CPL * l + v];
            if (RELU) o[v] = fmaxf(o[v], 0.f);
        }
        if constexpr (CPL == 8) {
            float4 o0 = { o[0], o[1], o[2], o[3] };
            float4 o1 = { o[4], o[5], o[6], o[7] };
            *(float4*)&out[(size_t)wid * DOUT + 8 * l] = o0;
            *(float4*)&out[(size_t)wid * DOUT + 8 * l + 4] = o1;
        } else {
            float4 ov = { o[0], o[1], o[2], o[3] };
            *(float4*)&out[(size_t)wid * DOUT + 4 * l] = ov;
        }
    }
}

// ---------- launch ----------

extern "C" void kernel_launch(void* const* d_in, const int* in_sizes, int n_in,
                              void* d_out, int out_size, void* d_ws, size_t ws_size,
                              hipStream_t stream) {
    const float* x     = (const float*)d_in[0];
    const int*   eidx  = (const int*)d_in[1];
    const float* eattr = (const float*)d_in[2];
    const int N = in_sizes[0] / 128;
    const int E = in_sizes[1] / 2;
    const int* src = eidx;
    const int* dst = eidx + E;

    char* ws = (char*)d_ws;
    size_t off = 0;
    auto alloc = [&](size_t bytes) -> void* {
        void* p = ws + off;
        off += (bytes + 255) & ~(size_t)255;
        return p;
    };
    float*  bufA     = (float*)alloc((size_t)N * 128 * sizeof(float));
    __half* hbuf     = (__half*)alloc((size_t)N * 128 * sizeof(__half));
    int*    deg      = (int*)alloc((size_t)N * sizeof(int));
    int*    rowstart = (int*)alloc((size_t)N * sizeof(int));
    int*    cursor   = (int*)alloc((size_t)N * sizeof(int));
    float*  hs       = (float*)alloc((size_t)N * sizeof(float));
    float*  hd       = (float*)alloc((size_t)N * sizeof(float));
    int4*   ed       = (int4*)alloc((size_t)E * sizeof(int4));
    float*  wea      = (float*)alloc(64 * sizeof(float));
    int*    partials = (int*)alloc(256 * sizeof(int));

    const int tb = 256;
    hipMemsetAsync(deg, 0, (size_t)N * sizeof(int), stream);

    k_count<<<(E + tb - 1) / tb, tb, 0, stream>>>(dst, deg, E);
    int nb = (N + 255) / 256;
    k_scan_block<<<nb, 256, 0, stream>>>(deg, rowstart, partials, N);
    k_scan_partials<<<1, 256, 0, stream>>>(partials, nb);
    k_add_offsets<<<nb, 256, 0, stream>>>(rowstart, cursor, partials, N);
    k_wea_all<<<1, 64, 0, stream>>>((const float*)d_in[6], (const float*)d_in[7],
                                    (const float*)d_in[12], (const float*)d_in[13],
                                    (const float*)d_in[18], (const float*)d_in[19], wea);
    k_fill_ext<<<(E + tb - 1) / tb, tb, 0, stream>>>(src, dst, eattr, wea, cursor, ed, E);

    int nwave_blocks = (N * 64 + tb - 1) / tb;

    // ---- layer 0 (128->128, relu) ----
    {
        const float* W   = (const float*)d_in[3];
        const float* as_ = (const float*)d_in[4];
        const float* ad_ = (const float*)d_in[5];
        const float* b   = (const float*)d_in[8];
        k_gemm_dots<128, 128><<<(N + 31) / 32, 256, 0, stream>>>(x, W, as_, ad_, hbuf, hs, hd, N);
        k_aggregate<128, true, 1><<<nwave_blocks, tb, 0, stream>>>(hbuf, rowstart, deg, ed, hs, hd, b, bufA, N);
    }
    // ---- layer 1 (128->128, relu) ----
    {
        const float* W   = (const float*)d_in[9];
        const float* as_ = (const float*)d_in[10];
        const float* ad_ = (const float*)d_in[11];
        const float* b   = (const float*)d_in[14];
        k_gemm_dots<128, 128><<<(N + 31) / 32, 256, 0, stream>>>(bufA, W, as_, ad_, hbuf, hs, hd, N);
        k_aggregate<128, true, 2><<<nwave_blocks, tb, 0, stream>>>(hbuf, rowstart, deg, ed, hs, hd, b, bufA, N);
    }
    // ---- layer 2 (128->64, no relu) ----
    {
        const float* W   = (const float*)d_in[15];
        const float* as_ = (const float*)d_in[16];
        const float* ad_ = (const float*)d_in[17];
        const float* b   = (const float*)d_in[20];
        k_gemm_dots<128, 64><<<(N + 63) / 64, 256, 0, stream>>>(bufA, W, as_, ad_, hbuf, hs, hd, N);
        k_aggregate<64, false, 3><<<nwave_blocks, tb, 0, stream>>>(hbuf, rowstart, deg, ed, hs, hd, b, (float*)d_out, N);
    }
}

// Round 9
// 271.122 us; speedup vs baseline: 4.1734x; 1.0119x over previous
//
#include <hip/hip_runtime.h>
#include <hip/hip_fp16.h>
#include <cstdint>

#define NEG_SLOPE 0.2f

// ---------- preprocessing ----------

__global__ void k_count(const int* __restrict__ dst, int* __restrict__ deg, int E) {
    int e = blockIdx.x * blockDim.x + threadIdx.x;
    if (e < E) atomicAdd(deg + dst[e], 1);
}

__global__ void k_scan_block(const int* __restrict__ in, int* __restrict__ out,
                             int* __restrict__ partials, int n) {
    __shared__ int s[256];
    int i = blockIdx.x * 256 + threadIdx.x;
    int v = (i < n) ? in[i] : 0;
    s[threadIdx.x] = v;
    __syncthreads();
    for (int off = 1; off < 256; off <<= 1) {
        int t = (threadIdx.x >= off) ? s[threadIdx.x - off] : 0;
        __syncthreads();
        s[threadIdx.x] += t;
        __syncthreads();
    }
    if (i < n) out[i] = s[threadIdx.x] - v;   // exclusive
    if (threadIdx.x == 255) partials[blockIdx.x] = s[255];
}

__global__ void k_scan_partials(int* __restrict__ partials, int nb) {
    __shared__ int s[256];
    int v = (threadIdx.x < nb) ? partials[threadIdx.x] : 0;
    s[threadIdx.x] = v;
    __syncthreads();
    for (int off = 1; off < 256; off <<= 1) {
        int t = (threadIdx.x >= off) ? s[threadIdx.x - off] : 0;
        __syncthreads();
        s[threadIdx.x] += t;
        __syncthreads();
    }
    if (threadIdx.x < nb) partials[threadIdx.x] = s[threadIdx.x] - v;  // exclusive
}

__global__ void k_add_offsets(int* __restrict__ rowstart, int* __restrict__ cursor,
                              const int* __restrict__ partials, int n) {
    int i = blockIdx.x * 256 + threadIdx.x;
    if (i >= n) return;
    int r = rowstart[i] + partials[blockIdx.x];
    rowstart[i] = r;
    cursor[i] = r;
}

__global__ void k_wea_all(const float* __restrict__ We0, const float* __restrict__ ae0,
                          const float* __restrict__ We1, const float* __restrict__ ae1,
                          const float* __restrict__ We2, const float* __restrict__ ae2,
                          float* __restrict__ wea) {
    int j = threadIdx.x;
    if (j >= 24) return;
    int layer = j >> 3, k = j & 7;
    const float* We = layer == 0 ? We0 : (layer == 1 ? We1 : We2);
    const float* ae = layer == 0 ? ae0 : (layer == 1 ? ae1 : ae2);
    int D = layer == 2 ? 64 : 128;
    float s = 0.f;
    for (int t = 0; t < D; t++) s = fmaf(We[(size_t)k * D + t], ae[t], s);
    wea[j] = s;
}

// CSR fill + per-edge attr dots for all 3 layers, ONE packed 8B record
// {u16 src, f16 d0, f16 d1, f16 d2}. Self-loop mean term recovered in the
// aggregate as mean(ead) over the row.
__global__ void k_fill_ext(const int* __restrict__ src, const int* __restrict__ dst,
                           const float* __restrict__ ea, const float* __restrict__ wea,
                           int* __restrict__ cursor, ushort4* __restrict__ ed, int E) {
    int e = blockIdx.x * blockDim.x + threadIdx.x;
    if (e >= E) return;
    int s = src[e];
    int pos = atomicAdd(cursor + dst[e], 1);
    float4 a0 = *(const float4*)&ea[(size_t)e * 8];
    float4 a1 = *(const float4*)&ea[(size_t)e * 8 + 4];
    float4 w00 = *(const float4*)&wea[0],  w01 = *(const float4*)&wea[4];
    float4 w10 = *(const float4*)&wea[8],  w11 = *(const float4*)&wea[12];
    float4 w20 = *(const float4*)&wea[16], w21 = *(const float4*)&wea[20];
    float d0 = a0.x*w00.x + a0.y*w00.y + a0.z*w00.z + a0.w*w00.w
             + a1.x*w01.x + a1.y*w01.y + a1.z*w01.z + a1.w*w01.w;
    float d1 = a0.x*w10.x + a0.y*w10.y + a0.z*w10.z + a0.w*w10.w
             + a1.x*w11.x + a1.y*w11.y + a1.z*w11.z + a1.w*w11.w;
    float d2 = a0.x*w20.x + a0.y*w20.y + a0.z*w20.z + a0.w*w20.w
             + a1.x*w21.x + a1.y*w21.y + a1.z*w21.z + a1.w*w21.w;
    ushort4 rec;
    rec.x = (unsigned short)s;
    rec.y = __half_as_ushort(__float2half(d0));
    rec.z = __half_as_ushort(__float2half(d1));
    rec.w = __half_as_ushort(__float2half(d2));
    ed[pos] = rec;
}

// ---------- fused GEMM + attention dots (fp16 H output), K-tiled LDS ----------

template<int DIN, int DOUT>
__global__ __launch_bounds__(256) void k_gemm_dots(
    const float* __restrict__ X, const float* __restrict__ W,
    const float* __restrict__ as_, const float* __restrict__ ad_,
    __half* __restrict__ H, float* __restrict__ hs, float* __restrict__ hd, int n)
{
    constexpr int GROUP = DOUT / 4;     // threads per row-quad (32 or 16)
    constexpr int BM = 4096 / DOUT;     // rows per block (32 or 64)
    constexpr int KT = 32;
    __shared__ float sX[BM * KT];
    __shared__ float sW[KT * DOUT];

    int tid = threadIdx.x;
    int row_base = blockIdx.x * BM;
    int rows_avail = n - row_base; if (rows_avail > BM) rows_avail = BM;

    int r0 = (tid / GROUP) * 4;
    int c0 = (tid % GROUP) * 4;

    float acc[4][4] = {};

    for (int kt = 0; kt < DIN; kt += KT) {
        {
            constexpr int XV = BM * KT / 4;
            float4* sXv = (float4*)sX;
#pragma unroll
            for (int i = tid; i < XV; i += 256) {
                int row = i / (KT / 4), cc = i % (KT / 4);
                if (row < rows_avail)
                    sXv[i] = *(const float4*)&X[(size_t)(row_base + row) * DIN + kt + cc * 4];
            }
        }
        {
            constexpr int WV = KT * DOUT / 4;
            float4* sWv = (float4*)sW;
            const float4* Wv = (const float4*)(W + (size_t)kt * DOUT);
#pragma unroll
            for (int i = tid; i < WV; i += 256) sWv[i] = Wv[i];
        }
        __syncthreads();

#pragma unroll 8
        for (int k = 0; k < KT; k++) {
            float4 w = *(const float4*)&sW[k * DOUT + c0];
            float xv[4];
#pragma unroll
            for (int i = 0; i < 4; i++) xv[i] = sX[(r0 + i) * KT + k];
#pragma unroll
            for (int i = 0; i < 4; i++) {
                acc[i][0] = fmaf(xv[i], w.x, acc[i][0]);
                acc[i][1] = fmaf(xv[i], w.y, acc[i][1]);
                acc[i][2] = fmaf(xv[i], w.z, acc[i][2]);
                acc[i][3] = fmaf(xv[i], w.w, acc[i][3]);
            }
        }
        __syncthreads();
    }

    float4 av = *(const float4*)&as_[c0];
    float4 dv = *(const float4*)&ad_[c0];

#pragma unroll
    for (int i = 0; i < 4; i++) {
        int row = row_base + r0 + i;
        bool ok = row < n;
        if (ok) {
            __half2 p0 = __floats2half2_rn(acc[i][0], acc[i][1]);
            __half2 p1 = __floats2half2_rn(acc[i][2], acc[i][3]);
            __half2* dst2 = (__half2*)&H[(size_t)row * DOUT + c0];
            dst2[0] = p0;
            dst2[1] = p1;
        }
        float ps = acc[i][0] * av.x + acc[i][1] * av.y + acc[i][2] * av.z + acc[i][3] * av.w;
        float pd = acc[i][0] * dv.x + acc[i][1] * dv.y + acc[i][2] * dv.z + acc[i][3] * dv.w;
#pragma unroll
        for (int off = GROUP / 2; off; off >>= 1) {
            ps += __shfl_xor(ps, off);
            pd += __shfl_xor(pd, off);
        }
        if (ok && (tid % GROUP) == 0) { hs[row] = ps; hd[row] = pd; }
    }
}

// ---------- fused alpha + softmax + aggregate ----------
// wave = four 16-lane groups; each group handles every 4th edge.
// One packed shfl per edge: (src<<16) | f16(ex).

template<int CPL>
__device__ __forceinline__ void accum_row16(float* acc, const __half* __restrict__ hrow,
                                            int l, float w) {
    if constexpr (CPL == 8) {
        float4 raw = *(const float4*)(hrow + 8 * l);
        __half2* h = (__half2*)&raw;
#pragma unroll
        for (int i = 0; i < 4; i++) {
            float2 f = __half22float2(h[i]);
            acc[2 * i]     = fmaf(w, f.x, acc[2 * i]);
            acc[2 * i + 1] = fmaf(w, f.y, acc[2 * i + 1]);
        }
    } else {
        float2 raw = *(const float2*)(hrow + 4 * l);
        __half2* h = (__half2*)&raw;
#pragma unroll
        for (int i = 0; i < 2; i++) {
            float2 f = __half22float2(h[i]);
            acc[2 * i]     = fmaf(w, f.x, acc[2 * i]);
            acc[2 * i + 1] = fmaf(w, f.y, acc[2 * i + 1]);
        }
    }
}

__device__ __forceinline__ float unpack_w(unsigned int p) {
    return __half2float(__ushort_as_half((unsigned short)(p & 0xFFFFu)));
}

template<int DOUT, bool RELU, int LCOMP>
__global__ void k_aggregate(const __half* __restrict__ H, const int* __restrict__ rowstart,
                            const int* __restrict__ deg, const ushort4* __restrict__ edata,
                            const float* __restrict__ hs, const float* __restrict__ hd,
                            const float* __restrict__ bias, float* __restrict__ out, int n) {
    int t = blockIdx.x * blockDim.x + threadIdx.x;
    int wid = t >> 6, lane = t & 63;
    if (wid >= n) return;
    int start = rowstart[wid], d = deg[wid];
    int quarter = lane >> 4, l = lane & 15;
    float hdv = hd[wid];
    float hsw = hs[wid];

    constexpr int CPL = DOUT / 16;
    float acc[CPL] = {};
    float denom;

    if (d <= 64) {
        // single-pass: one packed 8B load per edge, everything from registers
        float al = -3.0e38f; int s = 0; float eadv = 0.f;
        if (lane < d) {
            ushort4 pv = edata[start + lane];
            s = pv.x;
            unsigned short eu = (LCOMP == 1) ? pv.y : (LCOMP == 2) ? pv.z : pv.w;
            eadv = __half2float(__ushort_as_half(eu));
            float a = hs[s] + hdv + eadv;
            al = a > 0.f ? a : NEG_SLOPE * a;
        }
        // self-loop attr term = mean(ead) over the row
        float esum = (lane < d) ? eadv : 0.f;
#pragma unroll
        for (int off = 32; off; off >>= 1) esum += __shfl_xor(esum, off);
        int dd = d < 1 ? 1 : d;
        float aself = hsw + hdv + esum / (float)dd;
        aself = aself > 0.f ? aself : NEG_SLOPE * aself;

        float m = fmaxf(al, aself);
#pragma unroll
        for (int off = 32; off; off >>= 1) m = fmaxf(m, __shfl_xor(m, off));
        float ex = (lane < d) ? expf(al - m) : 0.f;
        float exsum = ex;
#pragma unroll
        for (int off = 32; off; off >>= 1) exsum += __shfl_xor(exsum, off);
        float exself = expf(aself - m);
        denom = exsum + exself;

        unsigned int pk = ((unsigned int)s << 16) |
                          (unsigned int)__half_as_ushort(__float2half(ex));

        if (quarter == 0) accum_row16<CPL>(acc, H + (size_t)wid * DOUT, l, exself);

        int quads = (d + 3) >> 2;
#pragma unroll 4
        for (int jj = 0; jj < quads; jj++) {
            int j = 4 * jj + quarter;
            unsigned int pj = (unsigned int)__shfl((int)pk, j);
            int sj = pj >> 16;
            float w = unpack_w(pj);
            if (j < d) accum_row16<CPL>(acc, H + ((size_t)sj << (CPL == 8 ? 7 : 6)), l, w);
        }
    } else {
        // two-pass chunked (rare)
        float m_e = -3.0e38f;
        float esum = 0.f;
        for (int base = 0; base < d; base += 64) {
            if (base + lane < d) {
                ushort4 pv = edata[start + base + lane];
                unsigned short eu = (LCOMP == 1) ? pv.y : (LCOMP == 2) ? pv.z : pv.w;
                float ev = __half2float(__ushort_as_half(eu));
                esum += ev;
                float a = hs[pv.x] + hdv + ev;
                a = a > 0.f ? a : NEG_SLOPE * a;
                m_e = fmaxf(m_e, a);
            }
        }
#pragma unroll
        for (int off = 32; off; off >>= 1) {
            m_e = fmaxf(m_e, __shfl_xor(m_e, off));
            esum += __shfl_xor(esum, off);
        }
        float aself = hsw + hdv + esum / (float)d;
        aself = aself > 0.f ? aself : NEG_SLOPE * aself;
        float m = fmaxf(m_e, aself);

        float exself = expf(aself - m);
        denom = exself;
        if (quarter == 0) accum_row16<CPL>(acc, H + (size_t)wid * DOUT, l, exself);

        for (int base = 0; base < d; base += 64) {
            int rem = d - base; if (rem > 64) rem = 64;
            float ex = 0.f; int s = 0;
            if (lane < rem) {
                ushort4 pv = edata[start + base + lane];
                s = pv.x;
                unsigned short eu = (LCOMP == 1) ? pv.y : (LCOMP == 2) ? pv.z : pv.w;
                float a = hs[s] + hdv + __half2float(__ushort_as_half(eu));
                a = a > 0.f ? a : NEG_SLOPE * a;
                ex = expf(a - m);
            }
            float exsum = ex;
#pragma unroll
            for (int off = 32; off; off >>= 1) exsum += __shfl_xor(exsum, off);
            denom += exsum;
            unsigned int pk = ((unsigned int)s << 16) |
                              (unsigned int)__half_as_ushort(__float2half(ex));
            int quads = (rem + 3) >> 2;
#pragma unroll 4
            for (int jj = 0; jj < quads; jj++) {
                int j = 4 * jj + quarter;
                unsigned int pj = (unsigned int)__shfl((int)pk, j);
                int sj = pj >> 16;
                float w = unpack_w(pj);
                if (j < rem) accum_row16<CPL>(acc, H + ((size_t)sj << (CPL == 8 ? 7 : 6)), l, w);
            }
        }
    }

    // combine the four 16-lane groups (same columns in each)
#pragma unroll
    for (int v = 0; v < CPL; v++) {
        acc[v] += __shfl_xor(acc[v], 16);
        acc[v] += __shfl_xor(acc[v], 32);
    }

    if (lane < 16) {
        float inv = 1.0f / (denom + 1e-16f);
        float o[CPL];
#pragma unroll
        for (int v = 0; v < CPL; v++) {
            o[v] = acc[v] * inv + bias[CPL * l + v];
            if (RELU) o[v] = fmaxf(o[v], 0.f);
        }
        if constexpr (CPL == 8) {
            float4 o0 = { o[0], o[1], o[2], o[3] };
            float4 o1 = { o[4], o[5], o[6], o[7] };
            *(float4*)&out[(size_t)wid * DOUT + 8 * l] = o0;
            *(float4*)&out[(size_t)wid * DOUT + 8 * l + 4] = o1;
        } else {
            float4 ov = { o[0], o[1], o[2], o[3] };
            *(float4*)&out[(size_t)wid * DOUT + 4 * l] = ov;
        }
    }
}

// ---------- launch ----------

extern "C" void kernel_launch(void* const* d_in, const int* in_sizes, int n_in,
                              void* d_out, int out_size, void* d_ws, size_t ws_size,
                              hipStream_t stream) {
    const float* x     = (const float*)d_in[0];
    const int*   eidx  = (const int*)d_in[1];
    const float* eattr = (const float*)d_in[2];
    const int N = in_sizes[0] / 128;
    const int E = in_sizes[1] / 2;
    const int* src = eidx;
    const int* dst = eidx + E;

    char* ws = (char*)d_ws;
    size_t off = 0;
    auto alloc = [&](size_t bytes) -> void* {
        void* p = ws + off;
        off += (bytes + 255) & ~(size_t)255;
        return p;
    };
    float*   bufA     = (float*)alloc((size_t)N * 128 * sizeof(float));
    __half*  hbuf     = (__half*)alloc((size_t)N * 128 * sizeof(__half));
    int*     deg      = (int*)alloc((size_t)N * sizeof(int));
    int*     rowstart = (int*)alloc((size_t)N * sizeof(int));
    int*     cursor   = (int*)alloc((size_t)N * sizeof(int));
    float*   hs       = (float*)alloc((size_t)N * sizeof(float));
    float*   hd       = (float*)alloc((size_t)N * sizeof(float));
    ushort4* ed       = (ushort4*)alloc((size_t)E * sizeof(ushort4));
    float*   wea      = (float*)alloc(64 * sizeof(float));
    int*     partials = (int*)alloc(256 * sizeof(int));

    const int tb = 256;
    hipMemsetAsync(deg, 0, (size_t)N * sizeof(int), stream);

    k_count<<<(E + tb - 1) / tb, tb, 0, stream>>>(dst, deg, E);
    int nb = (N + 255) / 256;
    k_scan_block<<<nb, 256, 0, stream>>>(deg, rowstart, partials, N);
    k_scan_partials<<<1, 256, 0, stream>>>(partials, nb);
    k_add_offsets<<<nb, 256, 0, stream>>>(rowstart, cursor, partials, N);
    k_wea_all<<<1, 64, 0, stream>>>((const float*)d_in[6], (const float*)d_in[7],
                                    (const float*)d_in[12], (const float*)d_in[13],
                                    (const float*)d_in[18], (const float*)d_in[19], wea);
    k_fill_ext<<<(E + tb - 1) / tb, tb, 0, stream>>>(src, dst, eattr, wea, cursor, ed, E);

    int nwave_blocks = (N * 64 + tb - 1) / tb;

    // ---- layer 0 (128->128, relu) ----
    {
        const float* W   = (const float*)d_in[3];
        const float* as_ = (const float*)d_in[4];
        const float* ad_ = (const float*)d_in[5];
        const float* b   = (const float*)d_in[8];
        k_gemm_dots<128, 128><<<(N + 31) / 32, 256, 0, stream>>>(x, W, as_, ad_, hbuf, hs, hd, N);
        k_aggregate<128, true, 1><<<nwave_blocks, tb, 0, stream>>>(hbuf, rowstart, deg, ed, hs, hd, b, bufA, N);
    }
    // ---- layer 1 (128->128, relu) ----
    {
        const float* W   = (const float*)d_in[9];
        const float* as_ = (const float*)d_in[10];
        const float* ad_ = (const float*)d_in[11];
        const float* b   = (const float*)d_in[14];
        k_gemm_dots<128, 128><<<(N + 31) / 32, 256, 0, stream>>>(bufA, W, as_, ad_, hbuf, hs, hd, N);
        k_aggregate<128, true, 2><<<nwave_blocks, tb, 0, stream>>>(hbuf, rowstart, deg, ed, hs, hd, b, bufA, N);
    }
    // ---- layer 2 (128->64, no relu) ----
    {
        const float* W   = (const float*)d_in[15];
        const float* as_ = (const float*)d_in[16];
        const float* ad_ = (const float*)d_in[17];
        const float* b   = (const float*)d_in[20];
        k_gemm_dots<128, 64><<<(N + 63) / 64, 256, 0, stream>>>(bufA, W, as_, ad_, hbuf, hs, hd, N);
        k_aggregate<64, false, 3><<<nwave_blocks, tb, 0, stream>>>(hbuf, rowstart, deg, ed, hs, hd, b, (float*)d_out, N);
    }
}

// Round 10
// 268.600 us; speedup vs baseline: 4.2126x; 1.0094x over previous
//
#include <hip/hip_runtime.h>
#include <hip/hip_fp16.h>
#include <cstdint>

#define NEG_SLOPE 0.2f
#define LOG2E 1.4426950408889634f

// ---------- preprocessing ----------

__global__ void k_zero(int* __restrict__ p, int n) {
    int i = blockIdx.x * blockDim.x + threadIdx.x;
    if (i < n) p[i] = 0;
}

__global__ void k_count(const int* __restrict__ dst, int* __restrict__ deg, int E) {
    int e = blockIdx.x * blockDim.x + threadIdx.x;
    if (e < E) atomicAdd(deg + dst[e], 1);
}

__global__ void k_scan_block(const int* __restrict__ in, int* __restrict__ out,
                             int* __restrict__ partials, int n) {
    __shared__ int s[256];
    int i = blockIdx.x * 256 + threadIdx.x;
    int v = (i < n) ? in[i] : 0;
    s[threadIdx.x] = v;
    __syncthreads();
    for (int off = 1; off < 256; off <<= 1) {
        int t = (threadIdx.x >= off) ? s[threadIdx.x - off] : 0;
        __syncthreads();
        s[threadIdx.x] += t;
        __syncthreads();
    }
    if (i < n) out[i] = s[threadIdx.x] - v;   // exclusive
    if (threadIdx.x == 255) partials[blockIdx.x] = s[255];
}

__global__ void k_scan_partials(int* __restrict__ partials, int nb) {
    __shared__ int s[256];
    int v = (threadIdx.x < nb) ? partials[threadIdx.x] : 0;
    s[threadIdx.x] = v;
    __syncthreads();
    for (int off = 1; off < 256; off <<= 1) {
        int t = (threadIdx.x >= off) ? s[threadIdx.x - off] : 0;
        __syncthreads();
        s[threadIdx.x] += t;
        __syncthreads();
    }
    if (threadIdx.x < nb) partials[threadIdx.x] = s[threadIdx.x] - v;  // exclusive
}

__global__ void k_add_offsets(int* __restrict__ rowstart, int* __restrict__ cursor,
                              const int* __restrict__ partials, int n) {
    int i = blockIdx.x * 256 + threadIdx.x;
    if (i >= n) return;
    int r = rowstart[i] + partials[blockIdx.x];
    rowstart[i] = r;
    cursor[i] = r;
}

__global__ void k_wea_all(const float* __restrict__ We0, const float* __restrict__ ae0,
                          const float* __restrict__ We1, const float* __restrict__ ae1,
                          const float* __restrict__ We2, const float* __restrict__ ae2,
                          float* __restrict__ wea) {
    int j = threadIdx.x;
    if (j >= 24) return;
    int layer = j >> 3, k = j & 7;
    const float* We = layer == 0 ? We0 : (layer == 1 ? We1 : We2);
    const float* ae = layer == 0 ? ae0 : (layer == 1 ? ae1 : ae2);
    int D = layer == 2 ? 64 : 128;
    float s = 0.f;
    for (int t = 0; t < D; t++) s = fmaf(We[(size_t)k * D + t], ae[t], s);
    wea[j] = s;
}

// CSR fill + per-edge attr dots for all 3 layers, ONE packed 8B record
// {u16 src, f16 d0, f16 d1, f16 d2}. Self-loop mean term recovered in the
// aggregate as mean(ead) over the row.
__global__ void k_fill_ext(const int* __restrict__ src, const int* __restrict__ dst,
                           const float* __restrict__ ea, const float* __restrict__ wea,
                           int* __restrict__ cursor, ushort4* __restrict__ ed, int E) {
    int e = blockIdx.x * blockDim.x + threadIdx.x;
    if (e >= E) return;
    int s = src[e];
    int pos = atomicAdd(cursor + dst[e], 1);
    float4 a0 = *(const float4*)&ea[(size_t)e * 8];
    float4 a1 = *(const float4*)&ea[(size_t)e * 8 + 4];
    float4 w00 = *(const float4*)&wea[0],  w01 = *(const float4*)&wea[4];
    float4 w10 = *(const float4*)&wea[8],  w11 = *(const float4*)&wea[12];
    float4 w20 = *(const float4*)&wea[16], w21 = *(const float4*)&wea[20];
    float d0 = a0.x*w00.x + a0.y*w00.y + a0.z*w00.z + a0.w*w00.w
             + a1.x*w01.x + a1.y*w01.y + a1.z*w01.z + a1.w*w01.w;
    float d1 = a0.x*w10.x + a0.y*w10.y + a0.z*w10.z + a0.w*w10.w
             + a1.x*w11.x + a1.y*w11.y + a1.z*w11.z + a1.w*w11.w;
    float d2 = a0.x*w20.x + a0.y*w20.y + a0.z*w20.z + a0.w*w20.w
             + a1.x*w21.x + a1.y*w21.y + a1.z*w21.z + a1.w*w21.w;
    ushort4 rec;
    rec.x = (unsigned short)s;
    rec.y = __half_as_ushort(__float2half(d0));
    rec.z = __half_as_ushort(__float2half(d1));
    rec.w = __half_as_ushort(__float2half(d2));
    ed[pos] = rec;
}

// ---------- fused GEMM + attention dots (fp16 H output), K-tiled LDS ----------

template<int DIN, int DOUT>
__global__ __launch_bounds__(256) void k_gemm_dots(
    const float* __restrict__ X, const float* __restrict__ W,
    const float* __restrict__ as_, const float* __restrict__ ad_,
    __half* __restrict__ H, float* __restrict__ hs, float* __restrict__ hd, int n)
{
    constexpr int GROUP = DOUT / 4;     // threads per row-quad (32 or 16)
    constexpr int BM = 4096 / DOUT;     // rows per block (32 or 64)
    constexpr int KT = 32;
    __shared__ float sX[BM * KT];
    __shared__ float sW[KT * DOUT];

    int tid = threadIdx.x;
    int row_base = blockIdx.x * BM;
    int rows_avail = n - row_base; if (rows_avail > BM) rows_avail = BM;

    int r0 = (tid / GROUP) * 4;
    int c0 = (tid % GROUP) * 4;

    float acc[4][4] = {};

    for (int kt = 0; kt < DIN; kt += KT) {
        {
            constexpr int XV = BM * KT / 4;
            float4* sXv = (float4*)sX;
#pragma unroll
            for (int i = tid; i < XV; i += 256) {
                int row = i / (KT / 4), cc = i % (KT / 4);
                if (row < rows_avail)
                    sXv[i] = *(const float4*)&X[(size_t)(row_base + row) * DIN + kt + cc * 4];
            }
        }
        {
            constexpr int WV = KT * DOUT / 4;
            float4* sWv = (float4*)sW;
            const float4* Wv = (const float4*)(W + (size_t)kt * DOUT);
#pragma unroll
            for (int i = tid; i < WV; i += 256) sWv[i] = Wv[i];
        }
        __syncthreads();

#pragma unroll 8
        for (int k = 0; k < KT; k++) {
            float4 w = *(const float4*)&sW[k * DOUT + c0];
            float xv[4];
#pragma unroll
            for (int i = 0; i < 4; i++) xv[i] = sX[(r0 + i) * KT + k];
#pragma unroll
            for (int i = 0; i < 4; i++) {
                acc[i][0] = fmaf(xv[i], w.x, acc[i][0]);
                acc[i][1] = fmaf(xv[i], w.y, acc[i][1]);
                acc[i][2] = fmaf(xv[i], w.z, acc[i][2]);
                acc[i][3] = fmaf(xv[i], w.w, acc[i][3]);
            }
        }
        __syncthreads();
    }

    float4 av = *(const float4*)&as_[c0];
    float4 dv = *(const float4*)&ad_[c0];

#pragma unroll
    for (int i = 0; i < 4; i++) {
        int row = row_base + r0 + i;
        bool ok = row < n;
        if (ok) {
            __half2 p0 = __floats2half2_rn(acc[i][0], acc[i][1]);
            __half2 p1 = __floats2half2_rn(acc[i][2], acc[i][3]);
            __half2* dst2 = (__half2*)&H[(size_t)row * DOUT + c0];
            dst2[0] = p0;
            dst2[1] = p1;
        }
        float ps = acc[i][0] * av.x + acc[i][1] * av.y + acc[i][2] * av.z + acc[i][3] * av.w;
        float pd = acc[i][0] * dv.x + acc[i][1] * dv.y + acc[i][2] * dv.z + acc[i][3] * dv.w;
#pragma unroll
        for (int off = GROUP / 2; off; off >>= 1) {
            ps += __shfl_xor(ps, off);
            pd += __shfl_xor(pd, off);
        }
        if (ok && (tid % GROUP) == 0) { hs[row] = ps; hd[row] = pd; }
    }
}

// ---------- fused alpha + softmax + aggregate ----------
// wave = four 16-lane groups; each group handles every 4th edge.
// One packed shfl per edge: (src<<16) | f16(ex). exp via v_exp_f32.

template<int CPL>
__device__ __forceinline__ void accum_row16(float* acc, const __half* __restrict__ hrow,
                                            int l, float w) {
    if constexpr (CPL == 8) {
        float4 raw = *(const float4*)(hrow + 8 * l);
        __half2* h = (__half2*)&raw;
#pragma unroll
        for (int i = 0; i < 4; i++) {
            float2 f = __half22float2(h[i]);
            acc[2 * i]     = fmaf(w, f.x, acc[2 * i]);
            acc[2 * i + 1] = fmaf(w, f.y, acc[2 * i + 1]);
        }
    } else {
        float2 raw = *(const float2*)(hrow + 4 * l);
        __half2* h = (__half2*)&raw;
#pragma unroll
        for (int i = 0; i < 2; i++) {
            float2 f = __half22float2(h[i]);
            acc[2 * i]     = fmaf(w, f.x, acc[2 * i]);
            acc[2 * i + 1] = fmaf(w, f.y, acc[2 * i + 1]);
        }
    }
}

__device__ __forceinline__ float unpack_w(unsigned int p) {
    return __half2float(__ushort_as_half((unsigned short)(p & 0xFFFFu)));
}

__device__ __forceinline__ float fexp(float x) {
    return exp2f(x * LOG2E);   // lowers to v_exp_f32
}

template<int DOUT, bool RELU, int LCOMP>
__global__ void k_aggregate(const __half* __restrict__ H, const int* __restrict__ rowstart,
                            const int* __restrict__ deg, const ushort4* __restrict__ edata,
                            const float* __restrict__ hs, const float* __restrict__ hd,
                            const float* __restrict__ bias, float* __restrict__ out, int n) {
    int t = blockIdx.x * blockDim.x + threadIdx.x;
    int wid = t >> 6, lane = t & 63;
    if (wid >= n) return;
    int start = rowstart[wid], d = deg[wid];
    int quarter = lane >> 4, l = lane & 15;
    float hdv = hd[wid];
    float hsw = hs[wid];

    constexpr int CPL = DOUT / 16;
    float acc[CPL] = {};
    float denom;

    if (d <= 64) {
        // single-pass: one packed 8B load per edge, everything from registers
        float al = -3.0e38f; int s = 0; float eadv = 0.f;
        if (lane < d) {
            ushort4 pv = edata[start + lane];
            s = pv.x;
            unsigned short eu = (LCOMP == 1) ? pv.y : (LCOMP == 2) ? pv.z : pv.w;
            eadv = __half2float(__ushort_as_half(eu));
            float a = hs[s] + hdv + eadv;
            al = a > 0.f ? a : NEG_SLOPE * a;
        }
        // merged butterflies: esum (self-loop mean term) and edge max
        float esum = (lane < d) ? eadv : 0.f;
        float m0 = al;
#pragma unroll
        for (int off = 32; off; off >>= 1) {
            esum += __shfl_xor(esum, off);
            m0 = fmaxf(m0, __shfl_xor(m0, off));
        }
        int dd = d < 1 ? 1 : d;
        float aself = hsw + hdv + esum / (float)dd;
        aself = aself > 0.f ? aself : NEG_SLOPE * aself;
        float m = fmaxf(m0, aself);

        float ex = (lane < d) ? fexp(al - m) : 0.f;
        float exsum = ex;
#pragma unroll
        for (int off = 32; off; off >>= 1) exsum += __shfl_xor(exsum, off);
        float exself = fexp(aself - m);
        denom = exsum + exself;

        unsigned int pk = ((unsigned int)s << 16) |
                          (unsigned int)__half_as_ushort(__float2half(ex));

        if (quarter == 0) accum_row16<CPL>(acc, H + (size_t)wid * DOUT, l, exself);

        int quads = (d + 3) >> 2;
#pragma unroll 4
        for (int jj = 0; jj < quads; jj++) {
            int j = 4 * jj + quarter;
            unsigned int pj = (unsigned int)__shfl((int)pk, j);
            int sj = pj >> 16;
            float w = unpack_w(pj);
            if (j < d) accum_row16<CPL>(acc, H + ((size_t)sj << (CPL == 8 ? 7 : 6)), l, w);
        }
    } else {
        // two-pass chunked (rare)
        float m_e = -3.0e38f;
        float esum = 0.f;
        for (int base = 0; base < d; base += 64) {
            if (base + lane < d) {
                ushort4 pv = edata[start + base + lane];
                unsigned short eu = (LCOMP == 1) ? pv.y : (LCOMP == 2) ? pv.z : pv.w;
                float ev = __half2float(__ushort_as_half(eu));
                esum += ev;
                float a = hs[pv.x] + hdv + ev;
                a = a > 0.f ? a : NEG_SLOPE * a;
                m_e = fmaxf(m_e, a);
            }
        }
#pragma unroll
        for (int off = 32; off; off >>= 1) {
            m_e = fmaxf(m_e, __shfl_xor(m_e, off));
            esum += __shfl_xor(esum, off);
        }
        float aself = hsw + hdv + esum / (float)d;
        aself = aself > 0.f ? aself : NEG_SLOPE * aself;
        float m = fmaxf(m_e, aself);

        float exself = fexp(aself - m);
        denom = exself;
        if (quarter == 0) accum_row16<CPL>(acc, H + (size_t)wid * DOUT, l, exself);

        for (int base = 0; base < d; base += 64) {
            int rem = d - base; if (rem > 64) rem = 64;
            float ex = 0.f; int s = 0;
            if (lane < rem) {
                ushort4 pv = edata[start + base + lane];
                s = pv.x;
                unsigned short eu = (LCOMP == 1) ? pv.y : (LCOMP == 2) ? pv.z : pv.w;
                float a = hs[s] + hdv + __half2float(__ushort_as_half(eu));
                a = a > 0.f ? a : NEG_SLOPE * a;
                ex = fexp(a - m);
            }
            float exsum = ex;
#pragma unroll
            for (int off = 32; off; off >>= 1) exsum += __shfl_xor(exsum, off);
            denom += exsum;
            unsigned int pk = ((unsigned int)s << 16) |
                              (unsigned int)__half_as_ushort(__float2half(ex));
            int quads = (rem + 3) >> 2;
#pragma unroll 4
            for (int jj = 0; jj < quads; jj++) {
                int j = 4 * jj + quarter;
                unsigned int pj = (unsigned int)__shfl((int)pk, j);
                int sj = pj >> 16;
                float w = unpack_w(pj);
                if (j < rem) accum_row16<CPL>(acc, H + ((size_t)sj << (CPL == 8 ? 7 : 6)), l, w);
            }
        }
    }

    // combine the four 16-lane groups (same columns in each)
#pragma unroll
    for (int v = 0; v < CPL; v++) {
        acc[v] += __shfl_xor(acc[v], 16);
        acc[v] += __shfl_xor(acc[v], 32);
    }

    if (lane < 16) {
        float inv = 1.0f / (denom + 1e-16f);
        float o[CPL];
#pragma unroll
        for (int v = 0; v < CPL; v++) {
            o[v] = acc[v] * inv + bias[CPL * l + v];
            if (RELU) o[v] = fmaxf(o[v], 0.f);
        }
        if constexpr (CPL == 8) {
            float4 o0 = { o[0], o[1], o[2], o[3] };
            float4 o1 = { o[4], o[5], o[6], o[7] };
            *(float4*)&out[(size_t)wid * DOUT + 8 * l] = o0;
            *(float4*)&out[(size_t)wid * DOUT + 8 * l + 4] = o1;
        } else {
            float4 ov = { o[0], o[1], o[2], o[3] };
            *(float4*)&out[(size_t)wid * DOUT + 4 * l] = ov;
        }
    }
}

// ---------- launch ----------

extern "C" void kernel_launch(void* const* d_in, const int* in_sizes, int n_in,
                              void* d_out, int out_size, void* d_ws, size_t ws_size,
                              hipStream_t stream) {
    const float* x     = (const float*)d_in[0];
    const int*   eidx  = (const int*)d_in[1];
    const float* eattr = (const float*)d_in[2];
    const int N = in_sizes[0] / 128;
    const int E = in_sizes[1] / 2;
    const int* src = eidx;
    const int* dst = eidx + E;

    char* ws = (char*)d_ws;
    size_t off = 0;
    auto alloc = [&](size_t bytes) -> void* {
        void* p = ws + off;
        off += (bytes + 255) & ~(size_t)255;
        return p;
    };
    float*   bufA     = (float*)alloc((size_t)N * 128 * sizeof(float));
    __half*  hbuf     = (__half*)alloc((size_t)N * 128 * sizeof(__half));
    int*     deg      = (int*)alloc((size_t)N * sizeof(int));
    int*     rowstart = (int*)alloc((size_t)N * sizeof(int));
    int*     cursor   = (int*)alloc((size_t)N * sizeof(int));
    float*   hs       = (float*)alloc((size_t)N * sizeof(float));
    float*   hd       = (float*)alloc((size_t)N * sizeof(float));
    ushort4* ed       = (ushort4*)alloc((size_t)E * sizeof(ushort4));
    float*   wea      = (float*)alloc(64 * sizeof(float));
    int*     partials = (int*)alloc(256 * sizeof(int));

    const int tb = 256;

    k_zero<<<(N + tb - 1) / tb, tb, 0, stream>>>(deg, N);
    k_count<<<(E + tb - 1) / tb, tb, 0, stream>>>(dst, deg, E);
    int nb = (N + 255) / 256;
    k_scan_block<<<nb, 256, 0, stream>>>(deg, rowstart, partials, N);
    k_scan_partials<<<1, 256, 0, stream>>>(partials, nb);
    k_add_offsets<<<nb, 256, 0, stream>>>(rowstart, cursor, partials, N);
    k_wea_all<<<1, 64, 0, stream>>>((const float*)d_in[6], (const float*)d_in[7],
                                    (const float*)d_in[12], (const float*)d_in[13],
                                    (const float*)d_in[18], (const float*)d_in[19], wea);
    k_fill_ext<<<(E + tb - 1) / tb, tb, 0, stream>>>(src, dst, eattr, wea, cursor, ed, E);

    int nwave_blocks = (N * 64 + tb - 1) / tb;

    // ---- layer 0 (128->128, relu) ----
    {
        const float* W   = (const float*)d_in[3];
        const float* as_ = (const float*)d_in[4];
        const float* ad_ = (const float*)d_in[5];
        const float* b   = (const float*)d_in[8];
        k_gemm_dots<128, 128><<<(N + 31) / 32, 256, 0, stream>>>(x, W, as_, ad_, hbuf, hs, hd, N);
        k_aggregate<128, true, 1><<<nwave_blocks, tb, 0, stream>>>(hbuf, rowstart, deg, ed, hs, hd, b, bufA, N);
    }
    // ---- layer 1 (128->128, relu) ----
    {
        const float* W   = (const float*)d_in[9];
        const float* as_ = (const float*)d_in[10];
        const float* ad_ = (const float*)d_in[11];
        const float* b   = (const float*)d_in[14];
        k_gemm_dots<128, 128><<<(N + 31) / 32, 256, 0, stream>>>(bufA, W, as_, ad_, hbuf, hs, hd, N);
        k_aggregate<128, true, 2><<<nwave_blocks, tb, 0, stream>>>(hbuf, rowstart, deg, ed, hs, hd, b, bufA, N);
    }
    // ---- layer 2 (128->64, no relu) ----
    {
        const float* W   = (const float*)d_in[15];
        const float* as_ = (const float*)d_in[16];
        const float* ad_ = (const float*)d_in[17];
        const float* b   = (const float*)d_in[20];
        k_gemm_dots<128, 64><<<(N + 63) / 64, 256, 0, stream>>>(bufA, W, as_, ad_, hbuf, hs, hd, N);
        k_aggregate<64, false, 3><<<nwave_blocks, tb, 0, stream>>>(hbuf, rowstart, deg, ed, hs, hd, b, (float*)d_out, N);
    }
}

// Round 11
// 257.272 us; speedup vs baseline: 4.3981x; 1.0440x over previous
//
#include <hip/hip_runtime.h>
#include <hip/hip_fp16.h>
#include <cstdint>

#define NEG_SLOPE 0.2f
#define LOG2E 1.4426950408889634f

// ---------- preprocessing ----------

__global__ void k_zero(int* __restrict__ p, int n) {
    int i = blockIdx.x * blockDim.x + threadIdx.x;
    if (i < n) p[i] = 0;
}

// count degrees AND record each edge's rank within its dst bucket
__global__ void k_count(const int* __restrict__ dst, int* __restrict__ deg,
                        unsigned short* __restrict__ rank, int E) {
    int e = blockIdx.x * blockDim.x + threadIdx.x;
    if (e < E) rank[e] = (unsigned short)atomicAdd(deg + dst[e], 1);
}

__global__ void k_scan_block(const int* __restrict__ in, int* __restrict__ out,
                             int* __restrict__ partials, int n) {
    __shared__ int s[256];
    int i = blockIdx.x * 256 + threadIdx.x;
    int v = (i < n) ? in[i] : 0;
    s[threadIdx.x] = v;
    __syncthreads();
    for (int off = 1; off < 256; off <<= 1) {
        int t = (threadIdx.x >= off) ? s[threadIdx.x - off] : 0;
        __syncthreads();
        s[threadIdx.x] += t;
        __syncthreads();
    }
    if (i < n) out[i] = s[threadIdx.x] - v;   // exclusive within block
    if (threadIdx.x == 255) partials[blockIdx.x] = s[255];
}

// each block adds sum(partials[0..bid)) to its rowstart chunk (nb <= 256)
__global__ void k_add_offsets(int* __restrict__ rowstart, const int* __restrict__ partials,
                              int n, int nb) {
    __shared__ int red[256];
    int bid = blockIdx.x, tid = threadIdx.x;
    int v = (tid < bid && tid < nb) ? partials[tid] : 0;
    red[tid] = v;
    __syncthreads();
#pragma unroll
    for (int off = 128; off; off >>= 1) {
        if (tid < off) red[tid] += red[tid + off];
        __syncthreads();
    }
    int base = red[0];
    int i = bid * 256 + tid;
    if (i < n) rowstart[i] += base;
}

// CSR fill (atomic-free: pos = rowstart[dst] + rank) + per-edge attr dots for
// all 3 layers, ONE packed 8B record {u16 src, f16 d0, f16 d1, f16 d2}.
// wea (We@ae per layer, 24 floats) computed per-block in LDS.
__global__ void k_fill_ext(const int* __restrict__ src, const int* __restrict__ dst,
                           const unsigned short* __restrict__ rank,
                           const int* __restrict__ rowstart,
                           const float* __restrict__ ea,
                           const float* __restrict__ We0, const float* __restrict__ ae0,
                           const float* __restrict__ We1, const float* __restrict__ ae1,
                           const float* __restrict__ We2, const float* __restrict__ ae2,
                           ushort4* __restrict__ ed, int E) {
    __shared__ float swea[24];
    int tid = threadIdx.x;
    if (tid < 24) {
        int layer = tid >> 3, k = tid & 7;
        const float* We = layer == 0 ? We0 : (layer == 1 ? We1 : We2);
        const float* ae = layer == 0 ? ae0 : (layer == 1 ? ae1 : ae2);
        int D = layer == 2 ? 64 : 128;
        float s = 0.f;
        for (int t = 0; t < D; t++) s = fmaf(We[(size_t)k * D + t], ae[t], s);
        swea[tid] = s;
    }
    __syncthreads();
    int e = blockIdx.x * blockDim.x + tid;
    if (e >= E) return;
    int s = src[e];
    int pos = rowstart[dst[e]] + (int)rank[e];
    float4 a0 = *(const float4*)&ea[(size_t)e * 8];
    float4 a1 = *(const float4*)&ea[(size_t)e * 8 + 4];
    float4 w00 = *(const float4*)&swea[0],  w01 = *(const float4*)&swea[4];
    float4 w10 = *(const float4*)&swea[8],  w11 = *(const float4*)&swea[12];
    float4 w20 = *(const float4*)&swea[16], w21 = *(const float4*)&swea[20];
    float d0 = a0.x*w00.x + a0.y*w00.y + a0.z*w00.z + a0.w*w00.w
             + a1.x*w01.x + a1.y*w01.y + a1.z*w01.z + a1.w*w01.w;
    float d1 = a0.x*w10.x + a0.y*w10.y + a0.z*w10.z + a0.w*w10.w
             + a1.x*w11.x + a1.y*w11.y + a1.z*w11.z + a1.w*w11.w;
    float d2 = a0.x*w20.x + a0.y*w20.y + a0.z*w20.z + a0.w*w20.w
             + a1.x*w21.x + a1.y*w21.y + a1.z*w21.z + a1.w*w21.w;
    ushort4 rec;
    rec.x = (unsigned short)s;
    rec.y = __half_as_ushort(__float2half(d0));
    rec.z = __half_as_ushort(__float2half(d1));
    rec.w = __half_as_ushort(__float2half(d2));
    ed[pos] = rec;
}

// ---------- fused GEMM + attention dots (fp16 H output), K-tiled LDS ----------

template<int DIN, int DOUT>
__global__ __launch_bounds__(256) void k_gemm_dots(
    const float* __restrict__ X, const float* __restrict__ W,
    const float* __restrict__ as_, const float* __restrict__ ad_,
    __half* __restrict__ H, float* __restrict__ hs, float* __restrict__ hd, int n)
{
    constexpr int GROUP = DOUT / 4;     // threads per row-quad (32 or 16)
    constexpr int BM = 4096 / DOUT;     // rows per block (32 or 64)
    constexpr int KT = 32;
    __shared__ float sX[BM * KT];
    __shared__ float sW[KT * DOUT];

    int tid = threadIdx.x;
    int row_base = blockIdx.x * BM;
    int rows_avail = n - row_base; if (rows_avail > BM) rows_avail = BM;

    int r0 = (tid / GROUP) * 4;
    int c0 = (tid % GROUP) * 4;

    float acc[4][4] = {};

    for (int kt = 0; kt < DIN; kt += KT) {
        {
            constexpr int XV = BM * KT / 4;
            float4* sXv = (float4*)sX;
#pragma unroll
            for (int i = tid; i < XV; i += 256) {
                int row = i / (KT / 4), cc = i % (KT / 4);
                if (row < rows_avail)
                    sXv[i] = *(const float4*)&X[(size_t)(row_base + row) * DIN + kt + cc * 4];
            }
        }
        {
            constexpr int WV = KT * DOUT / 4;
            float4* sWv = (float4*)sW;
            const float4* Wv = (const float4*)(W + (size_t)kt * DOUT);
#pragma unroll
            for (int i = tid; i < WV; i += 256) sWv[i] = Wv[i];
        }
        __syncthreads();

#pragma unroll 8
        for (int k = 0; k < KT; k++) {
            float4 w = *(const float4*)&sW[k * DOUT + c0];
            float xv[4];
#pragma unroll
            for (int i = 0; i < 4; i++) xv[i] = sX[(r0 + i) * KT + k];
#pragma unroll
            for (int i = 0; i < 4; i++) {
                acc[i][0] = fmaf(xv[i], w.x, acc[i][0]);
                acc[i][1] = fmaf(xv[i], w.y, acc[i][1]);
                acc[i][2] = fmaf(xv[i], w.z, acc[i][2]);
                acc[i][3] = fmaf(xv[i], w.w, acc[i][3]);
            }
        }
        __syncthreads();
    }

    float4 av = *(const float4*)&as_[c0];
    float4 dv = *(const float4*)&ad_[c0];

#pragma unroll
    for (int i = 0; i < 4; i++) {
        int row = row_base + r0 + i;
        bool ok = row < n;
        if (ok) {
            __half2 p0 = __floats2half2_rn(acc[i][0], acc[i][1]);
            __half2 p1 = __floats2half2_rn(acc[i][2], acc[i][3]);
            __half2* dst2 = (__half2*)&H[(size_t)row * DOUT + c0];
            dst2[0] = p0;
            dst2[1] = p1;
        }
        float ps = acc[i][0] * av.x + acc[i][1] * av.y + acc[i][2] * av.z + acc[i][3] * av.w;
        float pd = acc[i][0] * dv.x + acc[i][1] * dv.y + acc[i][2] * dv.z + acc[i][3] * dv.w;
#pragma unroll
        for (int off = GROUP / 2; off; off >>= 1) {
            ps += __shfl_xor(ps, off);
            pd += __shfl_xor(pd, off);
        }
        if (ok && (tid % GROUP) == 0) { hs[row] = ps; hd[row] = pd; }
    }
}

// ---------- fused alpha + softmax + aggregate ----------

template<int CPL>
__device__ __forceinline__ void accum_row16(float* acc, const __half* __restrict__ hrow,
                                            int l, float w) {
    if constexpr (CPL == 8) {
        float4 raw = *(const float4*)(hrow + 8 * l);
        __half2* h = (__half2*)&raw;
#pragma unroll
        for (int i = 0; i < 4; i++) {
            float2 f = __half22float2(h[i]);
            acc[2 * i]     = fmaf(w, f.x, acc[2 * i]);
            acc[2 * i + 1] = fmaf(w, f.y, acc[2 * i + 1]);
        }
    } else {
        float2 raw = *(const float2*)(hrow + 4 * l);
        __half2* h = (__half2*)&raw;
#pragma unroll
        for (int i = 0; i < 2; i++) {
            float2 f = __half22float2(h[i]);
            acc[2 * i]     = fmaf(w, f.x, acc[2 * i]);
            acc[2 * i + 1] = fmaf(w, f.y, acc[2 * i + 1]);
        }
    }
}

__device__ __forceinline__ float unpack_w(unsigned int p) {
    return __half2float(__ushort_as_half((unsigned short)(p & 0xFFFFu)));
}

__device__ __forceinline__ float fexp(float x) {
    return exp2f(x * LOG2E);   // lowers to v_exp_f32
}

template<int DOUT, bool RELU, int LCOMP>
__global__ void k_aggregate(const __half* __restrict__ H, const int* __restrict__ rowstart,
                            const int* __restrict__ deg, const ushort4* __restrict__ edata,
                            const float* __restrict__ hs, const float* __restrict__ hd,
                            const float* __restrict__ bias, float* __restrict__ out, int n) {
    int t = blockIdx.x * blockDim.x + threadIdx.x;
    int wid = t >> 6, lane = t & 63;
    if (wid >= n) return;
    int start = rowstart[wid], d = deg[wid];
    int quarter = lane >> 4, l = lane & 15;
    float hdv = hd[wid];
    float hsw = hs[wid];

    constexpr int CPL = DOUT / 16;
    float acc[CPL] = {};
    float denom;

    if (d <= 64) {
        float al = -3.0e38f; int s = 0; float eadv = 0.f;
        if (lane < d) {
            ushort4 pv = edata[start + lane];
            s = pv.x;
            unsigned short eu = (LCOMP == 1) ? pv.y : (LCOMP == 2) ? pv.z : pv.w;
            eadv = __half2float(__ushort_as_half(eu));
            float a = hs[s] + hdv + eadv;
            al = a > 0.f ? a : NEG_SLOPE * a;
        }
        float esum = (lane < d) ? eadv : 0.f;
        float m0 = al;
#pragma unroll
        for (int off = 32; off; off >>= 1) {
            esum += __shfl_xor(esum, off);
            m0 = fmaxf(m0, __shfl_xor(m0, off));
        }
        int dd = d < 1 ? 1 : d;
        float aself = hsw + hdv + esum / (float)dd;
        aself = aself > 0.f ? aself : NEG_SLOPE * aself;
        float m = fmaxf(m0, aself);

        float ex = (lane < d) ? fexp(al - m) : 0.f;
        float exsum = ex;
#pragma unroll
        for (int off = 32; off; off >>= 1) exsum += __shfl_xor(exsum, off);
        float exself = fexp(aself - m);
        denom = exsum + exself;

        unsigned int pk = ((unsigned int)s << 16) |
                          (unsigned int)__half_as_ushort(__float2half(ex));

        if (quarter == 0) accum_row16<CPL>(acc, H + (size_t)wid * DOUT, l, exself);

        int quads = (d + 3) >> 2;
#pragma unroll 4
        for (int jj = 0; jj < quads; jj++) {
            int j = 4 * jj + quarter;
            unsigned int pj = (unsigned int)__shfl((int)pk, j);
            int sj = pj >> 16;
            float w = unpack_w(pj);
            if (j < d) accum_row16<CPL>(acc, H + ((size_t)sj << (CPL == 8 ? 7 : 6)), l, w);
        }
    } else {
        float m_e = -3.0e38f;
        float esum = 0.f;
        for (int base = 0; base < d; base += 64) {
            if (base + lane < d) {
                ushort4 pv = edata[start + base + lane];
                unsigned short eu = (LCOMP == 1) ? pv.y : (LCOMP == 2) ? pv.z : pv.w;
                float ev = __half2float(__ushort_as_half(eu));
                esum += ev;
                float a = hs[pv.x] + hdv + ev;
                a = a > 0.f ? a : NEG_SLOPE * a;
                m_e = fmaxf(m_e, a);
            }
        }
#pragma unroll
        for (int off = 32; off; off >>= 1) {
            m_e = fmaxf(m_e, __shfl_xor(m_e, off));
            esum += __shfl_xor(esum, off);
        }
        float aself = hsw + hdv + esum / (float)d;
        aself = aself > 0.f ? aself : NEG_SLOPE * aself;
        float m = fmaxf(m_e, aself);

        float exself = fexp(aself - m);
        denom = exself;
        if (quarter == 0) accum_row16<CPL>(acc, H + (size_t)wid * DOUT, l, exself);

        for (int base = 0; base < d; base += 64) {
            int rem = d - base; if (rem > 64) rem = 64;
            float ex = 0.f; int s = 0;
            if (lane < rem) {
                ushort4 pv = edata[start + base + lane];
                s = pv.x;
                unsigned short eu = (LCOMP == 1) ? pv.y : (LCOMP == 2) ? pv.z : pv.w;
                float a = hs[s] + hdv + __half2float(__ushort_as_half(eu));
                a = a > 0.f ? a : NEG_SLOPE * a;
                ex = fexp(a - m);
            }
            float exsum = ex;
#pragma unroll
            for (int off = 32; off; off >>= 1) exsum += __shfl_xor(exsum, off);
            denom += exsum;
            unsigned int pk = ((unsigned int)s << 16) |
                              (unsigned int)__half_as_ushort(__float2half(ex));
            int quads = (rem + 3) >> 2;
#pragma unroll 4
            for (int jj = 0; jj < quads; jj++) {
                int j = 4 * jj + quarter;
                unsigned int pj = (unsigned int)__shfl((int)pk, j);
                int sj = pj >> 16;
                float w = unpack_w(pj);
                if (j < rem) accum_row16<CPL>(acc, H + ((size_t)sj << (CPL == 8 ? 7 : 6)), l, w);
            }
        }
    }

#pragma unroll
    for (int v = 0; v < CPL; v++) {
        acc[v] += __shfl_xor(acc[v], 16);
        acc[v] += __shfl_xor(acc[v], 32);
    }

    if (lane < 16) {
        float inv = 1.0f / (denom + 1e-16f);
        float o[CPL];
#pragma unroll
        for (int v = 0; v < CPL; v++) {
            o[v] = acc[v] * inv + bias[CPL * l + v];
            if (RELU) o[v] = fmaxf(o[v], 0.f);
        }
        if constexpr (CPL == 8) {
            float4 o0 = { o[0], o[1], o[2], o[3] };
            float4 o1 = { o[4], o[5], o[6], o[7] };
            *(float4*)&out[(size_t)wid * DOUT + 8 * l] = o0;
            *(float4*)&out[(size_t)wid * DOUT + 8 * l + 4] = o1;
        } else {
            float4 ov = { o[0], o[1], o[2], o[3] };
            *(float4*)&out[(size_t)wid * DOUT + 4 * l] = ov;
        }
    }
}

// ---------- launch ----------

extern "C" void kernel_launch(void* const* d_in, const int* in_sizes, int n_in,
                              void* d_out, int out_size, void* d_ws, size_t ws_size,
                              hipStream_t stream) {
    const float* x     = (const float*)d_in[0];
    const int*   eidx  = (const int*)d_in[1];
    const float* eattr = (const float*)d_in[2];
    const int N = in_sizes[0] / 128;
    const int E = in_sizes[1] / 2;
    const int* src = eidx;
    const int* dst = eidx + E;

    char* ws = (char*)d_ws;
    size_t off = 0;
    auto alloc = [&](size_t bytes) -> void* {
        void* p = ws + off;
        off += (bytes + 255) & ~(size_t)255;
        return p;
    };
    float*          bufA     = (float*)alloc((size_t)N * 128 * sizeof(float));
    __half*         hbuf     = (__half*)alloc((size_t)N * 128 * sizeof(__half));
    int*            deg      = (int*)alloc((size_t)N * sizeof(int));
    int*            rowstart = (int*)alloc((size_t)N * sizeof(int));
    float*          hs       = (float*)alloc((size_t)N * sizeof(float));
    float*          hd       = (float*)alloc((size_t)N * sizeof(float));
    ushort4*        ed       = (ushort4*)alloc((size_t)E * sizeof(ushort4));
    unsigned short* rank     = (unsigned short*)alloc((size_t)E * sizeof(unsigned short));
    int*            partials = (int*)alloc(256 * sizeof(int));

    const int tb = 256;

    k_zero<<<(N + tb - 1) / tb, tb, 0, stream>>>(deg, N);
    k_count<<<(E + tb - 1) / tb, tb, 0, stream>>>(dst, deg, rank, E);
    int nb = (N + 255) / 256;
    k_scan_block<<<nb, 256, 0, stream>>>(deg, rowstart, partials, N);
    k_add_offsets<<<nb, 256, 0, stream>>>(rowstart, partials, N, nb);
    k_fill_ext<<<(E + tb - 1) / tb, tb, 0, stream>>>(src, dst, rank, rowstart, eattr,
                                                     (const float*)d_in[6], (const float*)d_in[7],
                                                     (const float*)d_in[12], (const float*)d_in[13],
                                                     (const float*)d_in[18], (const float*)d_in[19],
                                                     ed, E);

    int nwave_blocks = (N * 64 + tb - 1) / tb;

    // ---- layer 0 (128->128, relu) ----
    {
        const float* W   = (const float*)d_in[3];
        const float* as_ = (const float*)d_in[4];
        const float* ad_ = (const float*)d_in[5];
        const float* b   = (const float*)d_in[8];
        k_gemm_dots<128, 128><<<(N + 31) / 32, 256, 0, stream>>>(x, W, as_, ad_, hbuf, hs, hd, N);
        k_aggregate<128, true, 1><<<nwave_blocks, tb, 0, stream>>>(hbuf, rowstart, deg, ed, hs, hd, b, bufA, N);
    }
    // ---- layer 1 (128->128, relu) ----
    {
        const float* W   = (const float*)d_in[9];
        const float* as_ = (const float*)d_in[10];
        const float* ad_ = (const float*)d_in[11];
        const float* b   = (const float*)d_in[14];
        k_gemm_dots<128, 128><<<(N + 31) / 32, 256, 0, stream>>>(bufA, W, as_, ad_, hbuf, hs, hd, N);
        k_aggregate<128, true, 2><<<nwave_blocks, tb, 0, stream>>>(hbuf, rowstart, deg, ed, hs, hd, b, bufA, N);
    }
    // ---- layer 2 (128->64, no relu) ----
    {
        const float* W   = (const float*)d_in[15];
        const float* as_ = (const float*)d_in[16];
        const float* ad_ = (const float*)d_in[17];
        const float* b   = (const float*)d_in[20];
        k_gemm_dots<128, 64><<<(N + 63) / 64, 256, 0, stream>>>(bufA, W, as_, ad_, hbuf, hs, hd, N);
        k_aggregate<64, false, 3><<<nwave_blocks, tb, 0, stream>>>(hbuf, rowstart, deg, ed, hs, hd, b, (float*)d_out, N);
    }
}